// Round 8
// baseline (255.893 us; speedup 1.0000x reference)
//
#include <hip/hip_runtime.h>
#include <hip/hip_bf16.h>

#define SIZE 1024
#define NH 16
#define HD 64
#define BB 2
#define SS 2048
#define MROWS (BB * SS)  // 4096
#define QT 256           // attn q-tile (64 rows per wave)
#define NQT (SS / QT)    // 8 q-tiles per (b,h)
#define NKT ((SS / 2) / 64)  // 16 k-tiles per S-half

using bf16 = __hip_bfloat16;
using frag16 = __attribute__((ext_vector_type(8))) short;   // 8 bf16 (4 VGPRs)
using f32x4 = __attribute__((ext_vector_type(4))) float;    // 4 fp32 acc
typedef unsigned int u32;

// async global->LDS, 16B per lane; lds dest = wave-uniform base + lane*16 (m97/m104)
__device__ __forceinline__ void glds16(const bf16* g, bf16* l) {
    __builtin_amdgcn_global_load_lds(
        (const __attribute__((address_space(1))) u32*)g,
        (__attribute__((address_space(3))) u32*)l, 16, 0, 0);
}

__device__ __forceinline__ void cvt_store8(bf16* dst, const float* src) {
    float4 a = *(const float4*)src;
    float4 b = *(const float4*)(src + 4);
    bf16 t[8];
    t[0] = __float2bfloat16(a.x); t[1] = __float2bfloat16(a.y);
    t[2] = __float2bfloat16(a.z); t[3] = __float2bfloat16(a.w);
    t[4] = __float2bfloat16(b.x); t[5] = __float2bfloat16(b.y);
    t[6] = __float2bfloat16(b.z); t[7] = __float2bfloat16(b.w);
    *(uint4*)dst = *(const uint4*)t;
}

// ---------------------------------------------------------------------------
// fp32 -> bf16 cast, flat grid: 16M elems / 8 per thread. (Frozen.)
// ---------------------------------------------------------------------------
__global__ __launch_bounds__(256) void cast_kernel(
    const float* __restrict__ Wq, const float* __restrict__ Wk,
    const float* __restrict__ Wv, const float* __restrict__ Wo,
    const float* __restrict__ q, const float* __restrict__ k,
    const float* __restrict__ v,
    bf16* __restrict__ Wb, bf16* __restrict__ qb,
    bf16* __restrict__ kb, bf16* __restrict__ vb)
{
    const size_t WN = (size_t)SIZE * SIZE;          // 1<<20
    const size_t AN = (size_t)MROWS * SIZE;         // 1<<22
    const size_t e = ((size_t)blockIdx.x * 256 + threadIdx.x) * 8;
    if (e < 4 * WN) {
        const int which = (int)(e >> 20);
        const size_t off = e & (WN - 1);
        const float* s = (which == 0) ? Wq : (which == 1) ? Wk : (which == 2) ? Wv : Wo;
        cvt_store8(Wb + e, s + off);
    } else {
        const size_t a = e - 4 * WN;
        const int which = (int)(a >> 22);
        const size_t off = a & (AN - 1);
        const float* s = (which == 0) ? q : (which == 1) ? k : v;
        bf16* d = (which == 0) ? qb : (which == 1) ? kb : vb;
        cvt_store8(d + off, s + off);
    }
}

// ---------------------------------------------------------------------------
// qkv GEMM: 128x128 tile, BK=32, glds16 both operands, dbuf, 1 barrier/kt,
// XCD-swizzled (R7-proven). (Frozen.)
// ---------------------------------------------------------------------------
__device__ __forceinline__ void gemm_body(
    const bf16* __restrict__ X, const bf16* __restrict__ W,
    const float* __restrict__ bias, bf16* __restrict__ Y, float scale, bool vt_mode,
    int bm, int bn)
{
    __shared__ __align__(16) bf16 smem[16384];   // As[2][4096] | Bs[2][4096]; tr reuse
    bf16* As = smem;                             // buf b at As + b*4096
    bf16* Bs = smem + 8192;

    const int tid = threadIdx.x;
    const int wave = tid >> 6;
    const int lane = tid & 63;
    const int lane15 = lane & 15;
    const int quad = lane >> 4;
    const int wm = (wave & 1) * 64;
    const int wn = (wave >> 1) * 64;

    f32x4 acc[4][4];
#pragma unroll
    for (int i = 0; i < 4; i++)
#pragma unroll
        for (int j = 0; j < 4; j++)
            acc[i][j] = (f32x4){0.f, 0.f, 0.f, 0.f};

    const int srow = lane >> 2;        // 0..15 within 16-row chunk
    const int scol = (lane & 3) * 8;   // 0/8/16/24

#define STAGE(KT, BUF)                                                         \
    {                                                                          \
        _Pragma("unroll")                                                      \
        for (int n = 0; n < 2; n++) {                                          \
            const int c = wave * 2 + n;   /* chunk 0..7, 16 rows each */       \
            glds16(X + (size_t)(bm + c * 16 + srow) * SIZE + (KT) * 32 + scol, \
                   As + (BUF) * 4096 + c * 512);                               \
            glds16(W + (size_t)(bn + c * 16 + srow) * SIZE + (KT) * 32 + scol, \
                   Bs + (BUF) * 4096 + c * 512);                               \
        }                                                                      \
    }

    // prologue: tile 0 (latency exposed once)
    STAGE(0, 0);
    __syncthreads();

    for (int kt = 0; kt < SIZE / 32; kt++) {
        const int buf = kt & 1;
        if (kt + 1 < SIZE / 32) STAGE(kt + 1, buf ^ 1);   // prefetch -> other buffer
        __builtin_amdgcn_sched_barrier(0);                // pin prefetch before compute

        frag16 a[4], b[4];
#pragma unroll
        for (int mi = 0; mi < 4; mi++)
            a[mi] = *(const frag16*)(As + buf * 4096 + (wm + mi * 16 + lane15) * 32 + quad * 8);
#pragma unroll
        for (int ni = 0; ni < 4; ni++)
            b[ni] = *(const frag16*)(Bs + buf * 4096 + (wn + ni * 16 + lane15) * 32 + quad * 8);
#pragma unroll
        for (int mi = 0; mi < 4; mi++)
#pragma unroll
            for (int ni = 0; ni < 4; ni++)
                acc[mi][ni] = __builtin_amdgcn_mfma_f32_16x16x32_bf16(
                    a[mi], b[ni], acc[mi][ni], 0, 0, 0);

        __syncthreads();   // drains prefetch glds16 (vmcnt0) AFTER compute; buf^1 ready
    }
#undef STAGE

    if (!vt_mode) {
        // C/D layout col=lane&15, row=quad*4+reg (m89/m91)
#pragma unroll
        for (int ni = 0; ni < 4; ni++) {
            const int col = bn + wn + ni * 16 + lane15;
            const float bv = bias[col];
#pragma unroll
            for (int mi = 0; mi < 4; mi++) {
                const int row = bm + wm + mi * 16 + quad * 4;
#pragma unroll
                for (int r = 0; r < 4; r++)
                    Y[(size_t)(row + r) * SIZE + col] =
                        __float2bfloat16((acc[mi][ni][r] + bv) * scale);
            }
        }
    } else {
        // transpose epilogue -> vt[b][h][d][s], coalesced 16B stores
        bf16* tr = smem;                   // [64][136] = 8704 elems, fits
        const int bloc = bm >> 11;
        const int s0g = bm & (SS - 1);
#pragma unroll
        for (int p = 0; p < 2; p++) {
            __syncthreads();
            if ((wave >> 1) == p) {
#pragma unroll
                for (int ni = 0; ni < 4; ni++) {
                    const int colp = ni * 16 + lane15;
                    const float bv = bias[bn + p * 64 + colp];
#pragma unroll
                    for (int mi = 0; mi < 4; mi++) {
                        const int row = wm + mi * 16 + quad * 4;
#pragma unroll
                        for (int r = 0; r < 4; r++)
                            tr[colp * 136 + row + r] =
                                __float2bfloat16(acc[mi][ni][r] + bv);
                    }
                }
            }
            __syncthreads();
            const int colp = tid >> 2;
            const int gcol = bn + p * 64 + colp;
            const int hh = gcol >> 6, dd = gcol & (HD - 1);
            bf16* dst = (bf16*)Y + ((size_t)(bloc * NH + hh) * HD + dd) * SS
                        + s0g + (tid & 3) * 32;
            const bf16* src = tr + colp * 136 + (tid & 3) * 32;
#pragma unroll
            for (int j = 0; j < 4; j++)
                *(uint4*)(dst + j * 8) = *(const uint4*)(src + j * 8);
        }
    }
}

// 1-D grid of 768; bijective XCD swizzle (nwg=768, 768%8==0, chunk=96):
// work w = (f%8)*96 + f/8; decode x-fastest (8 col-tiles, 32 row-tiles, 3 z)
__global__ __launch_bounds__(256) void qkv_proj_kernel(
    const bf16* __restrict__ qb, const bf16* __restrict__ kb, const bf16* __restrict__ vb,
    const bf16* __restrict__ Wb,
    const float* __restrict__ bq, const float* __restrict__ bk, const float* __restrict__ bv,
    bf16* __restrict__ qh, bf16* __restrict__ kh, bf16* __restrict__ vt)
{
    const int f = blockIdx.x;
    const int w = (f & 7) * 96 + (f >> 3);
    const int z = w >> 8;             // /256 (blocks per z-slice)
    const int rem = w & 255;
    const int bn = (rem & 7) * 128;   // col tile (x-fastest within chunk)
    const int bm = (rem >> 3) * 128;  // row tile

    const bf16 *X, *W; const float* bi; bf16* Y; float sc; bool vm;
    if (z == 0)      { X = qb; W = Wb;                   bi = bq; Y = qh; sc = 0.125f; vm = false; }
    else if (z == 1) { X = kb; W = Wb + SIZE * SIZE;     bi = bk; Y = kh; sc = 1.0f;   vm = false; }
    else             { X = vb; W = Wb + 2 * SIZE * SIZE; bi = bv; Y = vt; sc = 1.0f;   vm = true;  }
    gemm_body(X, W, bi, Y, sc, vm, bm, bn);
}

// ---------------------------------------------------------------------------
// Flash attention, split-S, QT=256 (64 q-rows/wave), NO K/V LDS STAGING.
// R7 accounting: LDS pipe (~30us incl conflicts) + 2 barriers/kt dominated.
// K-tile and V-tile are 8KB each, reused by all 4 waves and 8 qt-blocks per
// (b,h) -> L1/L2-resident (Common-mistake #7: don't stage cache-fit data).
// kf/bv fragments now load DIRECTLY from global (16B/lane; the kf0/kf1 pair
// consumes each 128B line fully). Deletes ~20 LDS instr/wave/kt, both
// __syncthreads (Ps stays wave-private + wave_barrier), and 36KB LDS.
// Grid flattened 512 with XCD swizzle: all 16 blocks of a (b,h) land on one
// XCD (4 bh x 1MB = 2MB < 4MB L2/XCD) so K/V is fetched from HBM once.
// ---------------------------------------------------------------------------
__global__ __launch_bounds__(256) void attn_kernel(
    const bf16* __restrict__ qh, const bf16* __restrict__ kh,
    const bf16* __restrict__ vt, bf16* __restrict__ po, float* __restrict__ pl)
{
    __shared__ __align__(16) bf16 Ps[4][64][72];   // 36,864 B (wave-private slabs)

    const int tid = threadIdx.x;
    const int wave = tid >> 6;
    const int lane = tid & 63;
    const int lane15 = lane & 15;
    const int quad = lane >> 4;

    // XCD swizzle: consecutive blockIdx round-robin XCDs (f%8 = xcd).
    // w = xcd*64 + f/8 -> per XCD a contiguous run of 64 work items =
    // 4 (b,h) pairs x 16 blocks (8 qt x 2 sh).
    const int f = blockIdx.x;
    const int w = (f & 7) * 64 + (f >> 3);
    const int bh = w >> 4;            // 0..31
    const int within = w & 15;
    const int b = bh >> 4;            // BB=2, NH=16
    const int h = bh & 15;
    const int qt = within >> 1;
    const int sh = within & 1;
    const int q0 = qt * QT;

    const size_t baseq = (size_t)b * SS * SIZE + (size_t)h * HD;
    const size_t basev = (size_t)(b * NH + h) * HD * SS;
    const float LOG2E = 1.44269504088896340736f;
    const float OFF = 12.0f * LOG2E;

    frag16 aq[4][2];
#pragma unroll
    for (int m = 0; m < 4; m++) {
        const int qrow = q0 + wave * 64 + m * 16 + lane15;
        const bf16* qp = qh + baseq + (size_t)qrow * SIZE + quad * 8;
        aq[m][0] = *(const frag16*)(qp);
        aq[m][1] = *(const frag16*)(qp + 32);
    }

    frag16 bones;
#pragma unroll
    for (int e = 0; e < 8; e++) bones[e] = (short)0x3F80;   // bf16 1.0

    f32x4 ofrag[4][4], l_frag[4];
#pragma unroll
    for (int m = 0; m < 4; m++) {
        l_frag[m] = (f32x4){0.f, 0.f, 0.f, 0.f};
#pragma unroll
        for (int dt = 0; dt < 4; dt++) ofrag[m][dt] = (f32x4){0.f, 0.f, 0.f, 0.f};
    }

    // per-lane base pointers for the strided fragment gathers
    const bf16* kbase = kh + baseq + (size_t)(sh * (SS / 2) + lane15) * SIZE + quad * 8;
    const bf16* vbase = vt + basev + (size_t)lane15 * SS + sh * (SS / 2) + quad * 8;

    for (int kt = 0; kt < NKT; kt++) {
        const int s0 = kt * 64;

        // ---- K/V fragments straight from global (L1/L2-resident tiles) ----
        frag16 kf[4][2], bv[4][2];
#pragma unroll
        for (int nt = 0; nt < 4; nt++) {
            const bf16* kp = kbase + (size_t)(s0 + nt * 16) * SIZE;
            kf[nt][0] = *(const frag16*)(kp);
            kf[nt][1] = *(const frag16*)(kp + 32);
        }
#pragma unroll
        for (int dt = 0; dt < 4; dt++) {
            const bf16* vp = vbase + (size_t)(dt * 16) * SS + s0;
            bv[dt][0] = *(const frag16*)(vp);
            bv[dt][1] = *(const frag16*)(vp + 32);
        }

        // ---- S^T = K Q^T, softmax, packed P store ----
#pragma unroll
        for (int m = 0; m < 4; m++) {
#pragma unroll
            for (int nt = 0; nt < 4; nt++) {
                f32x4 c = (f32x4){0.f, 0.f, 0.f, 0.f};
                c = __builtin_amdgcn_mfma_f32_16x16x32_bf16(kf[nt][0], aq[m][0], c, 0, 0, 0);
                c = __builtin_amdgcn_mfma_f32_16x16x32_bf16(kf[nt][1], aq[m][1], c, 0, 0, 0);
                // c[r] = S[q = m*16+lane15][key = nt*16 + quad*4 + r]
                bf16 p4[4];
#pragma unroll
                for (int r = 0; r < 4; r++)
                    p4[r] = __float2bfloat16(exp2f(c[r] * LOG2E - OFF));
                *(uint2*)&Ps[wave][m * 16 + lane15][nt * 16 + quad * 4] = *(const uint2*)p4;
            }
        }
        __builtin_amdgcn_wave_barrier();   // Ps wave-private; DS in-order per wave

        frag16 ap[4][2];
#pragma unroll
        for (int m = 0; m < 4; m++)
#pragma unroll
            for (int c2 = 0; c2 < 2; c2++)
                ap[m][c2] = *(const frag16*)&Ps[wave][m * 16 + lane15][c2 * 32 + quad * 8];

        __builtin_amdgcn_s_setprio(1);
        // ---- l += P @ 1 ----
#pragma unroll
        for (int m = 0; m < 4; m++)
#pragma unroll
            for (int c2 = 0; c2 < 2; c2++)
                l_frag[m] = __builtin_amdgcn_mfma_f32_16x16x32_bf16(
                    ap[m][c2], bones, l_frag[m], 0, 0, 0);

        // ---- O += P V ----
#pragma unroll
        for (int dt = 0; dt < 4; dt++) {
#pragma unroll
            for (int m = 0; m < 4; m++) {
                ofrag[m][dt] = __builtin_amdgcn_mfma_f32_16x16x32_bf16(ap[m][0], bv[dt][0], ofrag[m][dt], 0, 0, 0);
                ofrag[m][dt] = __builtin_amdgcn_mfma_f32_16x16x32_bf16(ap[m][1], bv[dt][1], ofrag[m][dt], 0, 0, 0);
            }
        }
        __builtin_amdgcn_s_setprio(0);
    }

    // ---- partial outputs (un-normalized O + row sums) ----
    const int pb = ((b * NH + h) * NQT + qt) * 2 + sh;
    if (lane15 == 0) {
        float* plp = pl + (size_t)pb * QT;
#pragma unroll
        for (int m = 0; m < 4; m++)
#pragma unroll
            for (int r = 0; r < 4; r++)
                plp[wave * 64 + m * 16 + quad * 4 + r] = l_frag[m][r];
    }
    bf16* pop = po + (size_t)pb * QT * HD;
#pragma unroll
    for (int m = 0; m < 4; m++)
#pragma unroll
        for (int dt = 0; dt < 4; dt++)
#pragma unroll
            for (int r = 0; r < 4; r++)
                pop[(size_t)(wave * 64 + m * 16 + quad * 4 + r) * HD + dt * 16 + lane15] =
                    __float2bfloat16(ofrag[m][dt][r]);
}

// ---------------------------------------------------------------------------
// Output projection with FUSED combine, XCD-swizzled (R7-proven). (Frozen.)
// ---------------------------------------------------------------------------
__global__ __launch_bounds__(256) void out_proj_kernel(
    const bf16* __restrict__ po, const float* __restrict__ pl,
    const bf16* __restrict__ Wob, const float* __restrict__ bo,
    float* __restrict__ out)
{
    __shared__ __align__(16) bf16 As[2 * 64 * 32];    // [2 planes][64][32]
    __shared__ __align__(16) bf16 Bs[2 * 128 * 32];   // [2 planes][128][32]

    const int f = blockIdx.x;
    const int w = (f & 7) * 64 + (f >> 3);    // bijective, nwg=512
    const int bn = (w & 7) * 128;             // col tile (x-fastest)
    const int bm = (w >> 3) * 64;             // row tile

    const int tid = threadIdx.x;
    const int wave = tid >> 6;
    const int lane = tid & 63;
    const int lane15 = lane & 15;
    const int quad = lane >> 4;
    const int wn = wave * 32;

    f32x4 acc[4][2];
#pragma unroll
    for (int i = 0; i < 4; i++)
#pragma unroll
        for (int j = 0; j < 2; j++)
            acc[i][j] = (f32x4){0.f, 0.f, 0.f, 0.f};

    const int srow = lane >> 2;        // 0..15
    const int scol = (lane & 3) * 8;

    const int arow = tid >> 2;
    const int acol = (tid & 3) * 8;
    const int gr = bm + arow;                 // global ctx row
    const int bIdx = gr >> 11;                // batch
    const int s = gr & (SS - 1);
    const int qt8 = s >> 8;                   // 256-row attn tile
    const int sq = s & (QT - 1);

    uint4 p0a, p1a, p0b, p1b;                 // {half0,half1} x {plane0,plane1}
    float l0, l1;

#define ALOAD(KT)                                                                 \
    {                                                                             \
        const int pb0_ = ((bIdx * NH + (KT)) * NQT + qt8) * 2;                    \
        const bf16* q0_ = po + (size_t)pb0_ * QT * HD + sq * HD;                  \
        const bf16* q1_ = po + (size_t)(pb0_ + 1) * QT * HD + sq * HD;            \
        p0a = *(const uint4*)(q0_ + acol);                                        \
        p0b = *(const uint4*)(q0_ + 32 + acol);                                   \
        p1a = *(const uint4*)(q1_ + acol);                                        \
        p1b = *(const uint4*)(q1_ + 32 + acol);                                   \
        l0 = pl[(size_t)pb0_ * QT + sq];                                          \
        l1 = pl[(size_t)(pb0_ + 1) * QT + sq];                                    \
    }

    ALOAD(0);

    for (int kt = 0; kt < NH; kt++) {         // 16 iterations, k0 = kt*64, h = kt
        __syncthreads();                      // prev readers done
        // ---- commit A (fused combine) ----
        {
            const float inv = 1.0f / fmaxf(l0 + l1, 1e-30f);
            const bf16* x0 = (const bf16*)&p0a; const bf16* y0 = (const bf16*)&p1a;
            const bf16* x1 = (const bf16*)&p0b; const bf16* y1 = (const bf16*)&p1b;
            bf16 o0[8], o1[8];
#pragma unroll
            for (int e = 0; e < 8; e++) {
                o0[e] = __float2bfloat16((__bfloat162float(x0[e]) + __bfloat162float(y0[e])) * inv);
                o1[e] = __float2bfloat16((__bfloat162float(x1[e]) + __bfloat162float(y1[e])) * inv);
            }
            *(uint4*)(As + 0 * 2048 + arow * 32 + acol) = *(const uint4*)o0;
            *(uint4*)(As + 1 * 2048 + arow * 32 + acol) = *(const uint4*)o1;
        }
        // ---- B glds16 staging ----
#pragma unroll
        for (int n = 0; n < 4; n++) {
            const int c = wave * 4 + n;
            const int plane = c >> 3;
            const int cc = c & 7;
            glds16(Wob + (size_t)(bn + cc * 16 + srow) * SIZE + kt * 64 + plane * 32 + scol,
                   Bs + c * 512);
        }
        __syncthreads();                      // drain ds_write + glds16

        if (kt + 1 < NH) ALOAD(kt + 1);       // prefetch flows under MFMAs

#pragma unroll
        for (int kk = 0; kk < 2; kk++) {
            frag16 a[4], b[2];
#pragma unroll
            for (int mi = 0; mi < 4; mi++)
                a[mi] = *(const frag16*)(As + kk * 2048 + (mi * 16 + lane15) * 32 + quad * 8);
#pragma unroll
            for (int ni = 0; ni < 2; ni++)
                b[ni] = *(const frag16*)(Bs + kk * 4096 + (wn + ni * 16 + lane15) * 32 + quad * 8);
#pragma unroll
            for (int mi = 0; mi < 4; mi++)
#pragma unroll
                for (int ni = 0; ni < 2; ni++)
                    acc[mi][ni] = __builtin_amdgcn_mfma_f32_16x16x32_bf16(
                        a[mi], b[ni], acc[mi][ni], 0, 0, 0);
        }
    }
#undef ALOAD

#pragma unroll
    for (int ni = 0; ni < 2; ni++) {
        const int col = bn + wn + ni * 16 + lane15;
        const float bv = bo[col];
#pragma unroll
        for (int mi = 0; mi < 4; mi++) {
            const int row = bm + mi * 16 + quad * 4;
#pragma unroll
            for (int r = 0; r < 4; r++)
                out[(size_t)(row + r) * SIZE + col] = acc[mi][ni][r] + bv;
        }
    }
}

extern "C" void kernel_launch(void* const* d_in, const int* in_sizes, int n_in,
                              void* d_out, int out_size, void* d_ws, size_t ws_size,
                              hipStream_t stream) {
    const float* q  = (const float*)d_in[0];
    const float* k  = (const float*)d_in[1];
    const float* v  = (const float*)d_in[2];
    const float* Wq = (const float*)d_in[3];
    const float* bq = (const float*)d_in[4];
    const float* Wk = (const float*)d_in[5];
    const float* bk = (const float*)d_in[6];
    const float* Wv = (const float*)d_in[7];
    const float* bv = (const float*)d_in[8];
    const float* Wo = (const float*)d_in[9];
    const float* bo = (const float*)d_in[10];
    float* out = (float*)d_out;

    // ws (bf16): Wb[4M] | qb | kb | vb | qh | kh | vt  (4.19M elems each)
    // aliases: po (8.39M) = qb+kb (dead after qkv); pl = Wq slot (dead after qkv)
    bf16* Wb  = (bf16*)d_ws;
    bf16* qb  = Wb + (size_t)4 * SIZE * SIZE;
    bf16* kb  = qb + (size_t)MROWS * SIZE;
    bf16* vb  = kb + (size_t)MROWS * SIZE;
    bf16* qh  = vb + (size_t)MROWS * SIZE;
    bf16* kh  = qh + (size_t)MROWS * SIZE;
    bf16* vt  = kh + (size_t)MROWS * SIZE;
    bf16* po  = qb;
    float* pl = (float*)Wb;

    cast_kernel<<<dim3(8192, 1, 1), 256, 0, stream>>>(
        Wq, Wk, Wv, Wo, q, k, v, Wb, qb, kb, vb);
    qkv_proj_kernel<<<dim3(768, 1, 1), 256, 0, stream>>>(
        qb, kb, vb, Wb, bq, bk, bv, qh, kh, vt);
    attn_kernel<<<dim3(512, 1, 1), 256, 0, stream>>>(qh, kh, vt, po, pl);
    out_proj_kernel<<<dim3(512, 1, 1), 256, 0, stream>>>(
        po, pl, Wb + (size_t)3 * SIZE * SIZE, bo, out);
}

// Round 9
// 253.641 us; speedup vs baseline: 1.0089x; 1.0089x over previous
//
#include <hip/hip_runtime.h>
#include <hip/hip_bf16.h>

#define SIZE 1024
#define NH 16
#define HD 64
#define BB 2
#define SS 2048
#define MROWS (BB * SS)  // 4096
#define QT 256           // attn q-tile (64 rows per wave)
#define NQT (SS / QT)    // 8 q-tiles per (b,h)
#define NKT ((SS / 2) / 64)  // 16 k-tiles per S-half

using bf16 = __hip_bfloat16;
using frag16 = __attribute__((ext_vector_type(8))) short;   // 8 bf16 (4 VGPRs)
using f32x4 = __attribute__((ext_vector_type(4))) float;    // 4 fp32 acc
typedef unsigned int u32;

// async global->LDS, 16B per lane; lds dest = wave-uniform base + lane*16 (m97/m104)
__device__ __forceinline__ void glds16(const bf16* g, bf16* l) {
    __builtin_amdgcn_global_load_lds(
        (const __attribute__((address_space(1))) u32*)g,
        (__attribute__((address_space(3))) u32*)l, 16, 0, 0);
}

__device__ __forceinline__ void cvt_store8(bf16* dst, const float* src) {
    float4 a = *(const float4*)src;
    float4 b = *(const float4*)(src + 4);
    bf16 t[8];
    t[0] = __float2bfloat16(a.x); t[1] = __float2bfloat16(a.y);
    t[2] = __float2bfloat16(a.z); t[3] = __float2bfloat16(a.w);
    t[4] = __float2bfloat16(b.x); t[5] = __float2bfloat16(b.y);
    t[6] = __float2bfloat16(b.z); t[7] = __float2bfloat16(b.w);
    *(uint4*)dst = *(const uint4*)t;
}

// ---------------------------------------------------------------------------
// fp32 -> bf16 cast, flat grid: 16M elems / 8 per thread. (Frozen.)
// ---------------------------------------------------------------------------
__global__ __launch_bounds__(256) void cast_kernel(
    const float* __restrict__ Wq, const float* __restrict__ Wk,
    const float* __restrict__ Wv, const float* __restrict__ Wo,
    const float* __restrict__ q, const float* __restrict__ k,
    const float* __restrict__ v,
    bf16* __restrict__ Wb, bf16* __restrict__ qb,
    bf16* __restrict__ kb, bf16* __restrict__ vb)
{
    const size_t WN = (size_t)SIZE * SIZE;          // 1<<20
    const size_t AN = (size_t)MROWS * SIZE;         // 1<<22
    const size_t e = ((size_t)blockIdx.x * 256 + threadIdx.x) * 8;
    if (e < 4 * WN) {
        const int which = (int)(e >> 20);
        const size_t off = e & (WN - 1);
        const float* s = (which == 0) ? Wq : (which == 1) ? Wk : (which == 2) ? Wv : Wo;
        cvt_store8(Wb + e, s + off);
    } else {
        const size_t a = e - 4 * WN;
        const int which = (int)(a >> 22);
        const size_t off = a & (AN - 1);
        const float* s = (which == 0) ? q : (which == 1) ? k : v;
        bf16* d = (which == 0) ? qb : (which == 1) ? kb : vb;
        cvt_store8(d + off, s + off);
    }
}

// ---------------------------------------------------------------------------
// qkv GEMM: 128x128 tile, BK=32, glds16 both operands, dbuf, 1 barrier/kt,
// XCD-swizzled (R7-proven). (Frozen.)
// ---------------------------------------------------------------------------
__device__ __forceinline__ void gemm_body(
    const bf16* __restrict__ X, const bf16* __restrict__ W,
    const float* __restrict__ bias, bf16* __restrict__ Y, float scale, bool vt_mode,
    int bm, int bn)
{
    __shared__ __align__(16) bf16 smem[16384];   // As[2][4096] | Bs[2][4096]; tr reuse
    bf16* As = smem;                             // buf b at As + b*4096
    bf16* Bs = smem + 8192;

    const int tid = threadIdx.x;
    const int wave = tid >> 6;
    const int lane = tid & 63;
    const int lane15 = lane & 15;
    const int quad = lane >> 4;
    const int wm = (wave & 1) * 64;
    const int wn = (wave >> 1) * 64;

    f32x4 acc[4][4];
#pragma unroll
    for (int i = 0; i < 4; i++)
#pragma unroll
        for (int j = 0; j < 4; j++)
            acc[i][j] = (f32x4){0.f, 0.f, 0.f, 0.f};

    const int srow = lane >> 2;        // 0..15 within 16-row chunk
    const int scol = (lane & 3) * 8;   // 0/8/16/24

#define STAGE(KT, BUF)                                                         \
    {                                                                          \
        _Pragma("unroll")                                                      \
        for (int n = 0; n < 2; n++) {                                          \
            const int c = wave * 2 + n;   /* chunk 0..7, 16 rows each */       \
            glds16(X + (size_t)(bm + c * 16 + srow) * SIZE + (KT) * 32 + scol, \
                   As + (BUF) * 4096 + c * 512);                               \
            glds16(W + (size_t)(bn + c * 16 + srow) * SIZE + (KT) * 32 + scol, \
                   Bs + (BUF) * 4096 + c * 512);                               \
        }                                                                      \
    }

    // prologue: tile 0 (latency exposed once)
    STAGE(0, 0);
    __syncthreads();

    for (int kt = 0; kt < SIZE / 32; kt++) {
        const int buf = kt & 1;
        if (kt + 1 < SIZE / 32) STAGE(kt + 1, buf ^ 1);   // prefetch -> other buffer
        __builtin_amdgcn_sched_barrier(0);                // pin prefetch before compute

        frag16 a[4], b[4];
#pragma unroll
        for (int mi = 0; mi < 4; mi++)
            a[mi] = *(const frag16*)(As + buf * 4096 + (wm + mi * 16 + lane15) * 32 + quad * 8);
#pragma unroll
        for (int ni = 0; ni < 4; ni++)
            b[ni] = *(const frag16*)(Bs + buf * 4096 + (wn + ni * 16 + lane15) * 32 + quad * 8);
#pragma unroll
        for (int mi = 0; mi < 4; mi++)
#pragma unroll
            for (int ni = 0; ni < 4; ni++)
                acc[mi][ni] = __builtin_amdgcn_mfma_f32_16x16x32_bf16(
                    a[mi], b[ni], acc[mi][ni], 0, 0, 0);

        __syncthreads();   // drains prefetch glds16 (vmcnt0) AFTER compute; buf^1 ready
    }
#undef STAGE

    if (!vt_mode) {
        // C/D layout col=lane&15, row=quad*4+reg (m89/m91)
#pragma unroll
        for (int ni = 0; ni < 4; ni++) {
            const int col = bn + wn + ni * 16 + lane15;
            const float bv = bias[col];
#pragma unroll
            for (int mi = 0; mi < 4; mi++) {
                const int row = bm + wm + mi * 16 + quad * 4;
#pragma unroll
                for (int r = 0; r < 4; r++)
                    Y[(size_t)(row + r) * SIZE + col] =
                        __float2bfloat16((acc[mi][ni][r] + bv) * scale);
            }
        }
    } else {
        // transpose epilogue -> vt[b][h][d][s], coalesced 16B stores
        bf16* tr = smem;                   // [64][136] = 8704 elems, fits
        const int bloc = bm >> 11;
        const int s0g = bm & (SS - 1);
#pragma unroll
        for (int p = 0; p < 2; p++) {
            __syncthreads();
            if ((wave >> 1) == p) {
#pragma unroll
                for (int ni = 0; ni < 4; ni++) {
                    const int colp = ni * 16 + lane15;
                    const float bv = bias[bn + p * 64 + colp];
#pragma unroll
                    for (int mi = 0; mi < 4; mi++) {
                        const int row = wm + mi * 16 + quad * 4;
#pragma unroll
                        for (int r = 0; r < 4; r++)
                            tr[colp * 136 + row + r] =
                                __float2bfloat16(acc[mi][ni][r] + bv);
                    }
                }
            }
            __syncthreads();
            const int colp = tid >> 2;
            const int gcol = bn + p * 64 + colp;
            const int hh = gcol >> 6, dd = gcol & (HD - 1);
            bf16* dst = (bf16*)Y + ((size_t)(bloc * NH + hh) * HD + dd) * SS
                        + s0g + (tid & 3) * 32;
            const bf16* src = tr + colp * 136 + (tid & 3) * 32;
#pragma unroll
            for (int j = 0; j < 4; j++)
                *(uint4*)(dst + j * 8) = *(const uint4*)(src + j * 8);
        }
    }
}

// 1-D grid of 768; bijective XCD swizzle (nwg=768, 768%8==0, chunk=96):
// work w = (f%8)*96 + f/8; decode x-fastest (8 col-tiles, 32 row-tiles, 3 z)
__global__ __launch_bounds__(256) void qkv_proj_kernel(
    const bf16* __restrict__ qb, const bf16* __restrict__ kb, const bf16* __restrict__ vb,
    const bf16* __restrict__ Wb,
    const float* __restrict__ bq, const float* __restrict__ bk, const float* __restrict__ bv,
    bf16* __restrict__ qh, bf16* __restrict__ kh, bf16* __restrict__ vt)
{
    const int f = blockIdx.x;
    const int w = (f & 7) * 96 + (f >> 3);
    const int z = w >> 8;             // /256 (blocks per z-slice)
    const int rem = w & 255;
    const int bn = (rem & 7) * 128;   // col tile (x-fastest within chunk)
    const int bm = (rem >> 3) * 128;  // row tile

    const bf16 *X, *W; const float* bi; bf16* Y; float sc; bool vm;
    if (z == 0)      { X = qb; W = Wb;                   bi = bq; Y = qh; sc = 0.125f; vm = false; }
    else if (z == 1) { X = kb; W = Wb + SIZE * SIZE;     bi = bk; Y = kh; sc = 1.0f;   vm = false; }
    else             { X = vb; W = Wb + 2 * SIZE * SIZE; bi = bv; Y = vt; sc = 1.0f;   vm = true;  }
    gemm_body(X, W, bi, Y, sc, vm, bm, bn);
}

// ---------------------------------------------------------------------------
// Flash attention, split-S, QT=256 (64 q-rows/wave), hybrid staging:
//   K: LDS-staged, double-buffered, ISSUE-early/COMMIT-late, 1 barrier/kt
//      (R7-proven pipeline -- kf feeds QK^T immediately, latency-critical).
//   V: destaged, fragments straight from global (consumed ~500cy later after
//      softmax -> latency hidden; deletes Vs LDS traffic + half the staging).
// R8 lesson: destaging K exposed its load latency (+9us); V-destage is the
// benign half. XCD swizzle kept (R8: FETCH 41->12.4MB).
// ---------------------------------------------------------------------------
__global__ __launch_bounds__(256) void attn_kernel(
    const bf16* __restrict__ qh, const bf16* __restrict__ kh,
    const bf16* __restrict__ vt, bf16* __restrict__ po, float* __restrict__ pl)
{
    __shared__ __align__(16) bf16 Ks[2][64][72];   // 18,432 B
    __shared__ __align__(16) bf16 Ps[4][64][72];   // 36,864 B (wave-private slabs)

    const int tid = threadIdx.x;
    const int wave = tid >> 6;
    const int lane = tid & 63;
    const int lane15 = lane & 15;
    const int quad = lane >> 4;

    // XCD swizzle: w = xcd*64 + f/8 -> per XCD a contiguous run of 64 work
    // items = 4 (b,h) pairs x 16 blocks (8 qt x 2 sh); K/V working set
    // 4 x 1MB = 2MB < 4MB L2/XCD.
    const int f = blockIdx.x;
    const int w = (f & 7) * 64 + (f >> 3);
    const int bh = w >> 4;            // 0..31
    const int within = w & 15;
    const int b = bh >> 4;            // BB=2, NH=16
    const int h = bh & 15;
    const int qt = within >> 1;
    const int sh = within & 1;
    const int q0 = qt * QT;

    const size_t baseq = (size_t)b * SS * SIZE + (size_t)h * HD;
    const size_t basev = (size_t)(b * NH + h) * HD * SS;
    const float LOG2E = 1.44269504088896340736f;
    const float OFF = 12.0f * LOG2E;

    frag16 aq[4][2];
#pragma unroll
    for (int m = 0; m < 4; m++) {
        const int qrow = q0 + wave * 64 + m * 16 + lane15;
        const bf16* qp = qh + baseq + (size_t)qrow * SIZE + quad * 8;
        aq[m][0] = *(const frag16*)(qp);
        aq[m][1] = *(const frag16*)(qp + 32);
    }

    frag16 bones;
#pragma unroll
    for (int e = 0; e < 8; e++) bones[e] = (short)0x3F80;   // bf16 1.0

    f32x4 ofrag[4][4], l_frag[4];
#pragma unroll
    for (int m = 0; m < 4; m++) {
        l_frag[m] = (f32x4){0.f, 0.f, 0.f, 0.f};
#pragma unroll
        for (int dt = 0; dt < 4; dt++) ofrag[m][dt] = (f32x4){0.f, 0.f, 0.f, 0.f};
    }

    const int sr = tid >> 3;          // 0..31 (K staging rows)
    const int sc = (tid & 7) * 8;

    // V per-lane base (destaged; d = lane15 + dt*16, key = sh*1024 + s0 + quad*8)
    const bf16* vbase = vt + basev + (size_t)lane15 * SS + sh * (SS / 2) + quad * 8;

    uint4 rk0, rk1;                    // K tile in flight
#define ISSUE_K(KT)                                                            \
    {                                                                          \
        const int s0_ = sh * (SS / 2) + (KT) * 64;                             \
        rk0 = *(const uint4*)(kh + baseq + (size_t)(s0_ + sr) * SIZE + sc);    \
        rk1 = *(const uint4*)(kh + baseq + (size_t)(s0_ + sr + 32) * SIZE + sc);\
    }
#define COMMIT_K(BUF)                                                          \
    {                                                                          \
        *(uint4*)&Ks[BUF][sr][sc] = rk0; *(uint4*)&Ks[BUF][sr + 32][sc] = rk1; \
    }

    // prologue: K tile 0 (latency exposed once)
    ISSUE_K(0); COMMIT_K(0);
    __syncthreads();

    for (int kt = 0; kt < NKT; kt++) {
        const int buf = kt & 1;
        const int s0 = kt * 64;
        if (kt + 1 < NKT) ISSUE_K(kt + 1);        // K prefetch in flight

        // V fragments for THIS kt: issued now, consumed after softmax (hidden)
        frag16 bv[4][2];
#pragma unroll
        for (int dt = 0; dt < 4; dt++) {
            const bf16* vp = vbase + (size_t)(dt * 16) * SS + s0;
            bv[dt][0] = *(const frag16*)(vp);
            bv[dt][1] = *(const frag16*)(vp + 32);
        }
        __builtin_amdgcn_sched_barrier(0);        // pin loads before compute

        // ---- S^T = K Q^T, softmax, packed P store ----
        frag16 kf[4][2];
#pragma unroll
        for (int nt = 0; nt < 4; nt++) {
            kf[nt][0] = *(const frag16*)&Ks[buf][nt * 16 + lane15][quad * 8];
            kf[nt][1] = *(const frag16*)&Ks[buf][nt * 16 + lane15][32 + quad * 8];
        }
#pragma unroll
        for (int m = 0; m < 4; m++) {
#pragma unroll
            for (int nt = 0; nt < 4; nt++) {
                f32x4 c = (f32x4){0.f, 0.f, 0.f, 0.f};
                c = __builtin_amdgcn_mfma_f32_16x16x32_bf16(kf[nt][0], aq[m][0], c, 0, 0, 0);
                c = __builtin_amdgcn_mfma_f32_16x16x32_bf16(kf[nt][1], aq[m][1], c, 0, 0, 0);
                // c[r] = S[q = m*16+lane15][key = nt*16 + quad*4 + r]
                bf16 p4[4];
#pragma unroll
                for (int r = 0; r < 4; r++)
                    p4[r] = __float2bfloat16(exp2f(c[r] * LOG2E - OFF));
                *(uint2*)&Ps[wave][m * 16 + lane15][nt * 16 + quad * 4] = *(const uint2*)p4;
            }
        }
        __builtin_amdgcn_wave_barrier();   // Ps wave-private; DS in-order per wave

        frag16 ap[4][2];
#pragma unroll
        for (int m = 0; m < 4; m++)
#pragma unroll
            for (int c2 = 0; c2 < 2; c2++)
                ap[m][c2] = *(const frag16*)&Ps[wave][m * 16 + lane15][c2 * 32 + quad * 8];

        __builtin_amdgcn_s_setprio(1);
        // ---- l += P @ 1 ----
#pragma unroll
        for (int m = 0; m < 4; m++)
#pragma unroll
            for (int c2 = 0; c2 < 2; c2++)
                l_frag[m] = __builtin_amdgcn_mfma_f32_16x16x32_bf16(
                    ap[m][c2], bones, l_frag[m], 0, 0, 0);

        // ---- O += P V ----
#pragma unroll
        for (int dt = 0; dt < 4; dt++) {
#pragma unroll
            for (int m = 0; m < 4; m++) {
                ofrag[m][dt] = __builtin_amdgcn_mfma_f32_16x16x32_bf16(ap[m][0], bv[dt][0], ofrag[m][dt], 0, 0, 0);
                ofrag[m][dt] = __builtin_amdgcn_mfma_f32_16x16x32_bf16(ap[m][1], bv[dt][1], ofrag[m][dt], 0, 0, 0);
            }
        }
        __builtin_amdgcn_s_setprio(0);

        if (kt + 1 < NKT) {
            COMMIT_K(buf ^ 1);                    // K prefetch landed by now
            __syncthreads();
        }
    }
#undef ISSUE_K
#undef COMMIT_K

    // ---- partial outputs (un-normalized O + row sums) ----
    const int pb = ((b * NH + h) * NQT + qt) * 2 + sh;
    if (lane15 == 0) {
        float* plp = pl + (size_t)pb * QT;
#pragma unroll
        for (int m = 0; m < 4; m++)
#pragma unroll
            for (int r = 0; r < 4; r++)
                plp[wave * 64 + m * 16 + quad * 4 + r] = l_frag[m][r];
    }
    bf16* pop = po + (size_t)pb * QT * HD;
#pragma unroll
    for (int m = 0; m < 4; m++)
#pragma unroll
        for (int dt = 0; dt < 4; dt++)
#pragma unroll
            for (int r = 0; r < 4; r++)
                pop[(size_t)(wave * 64 + m * 16 + quad * 4 + r) * HD + dt * 16 + lane15] =
                    __float2bfloat16(ofrag[m][dt][r]);
}

// ---------------------------------------------------------------------------
// Output projection with FUSED combine, XCD-swizzled (R7-proven). (Frozen.)
// ---------------------------------------------------------------------------
__global__ __launch_bounds__(256) void out_proj_kernel(
    const bf16* __restrict__ po, const float* __restrict__ pl,
    const bf16* __restrict__ Wob, const float* __restrict__ bo,
    float* __restrict__ out)
{
    __shared__ __align__(16) bf16 As[2 * 64 * 32];    // [2 planes][64][32]
    __shared__ __align__(16) bf16 Bs[2 * 128 * 32];   // [2 planes][128][32]

    const int f = blockIdx.x;
    const int w = (f & 7) * 64 + (f >> 3);    // bijective, nwg=512
    const int bn = (w & 7) * 128;             // col tile (x-fastest)
    const int bm = (w >> 3) * 64;             // row tile

    const int tid = threadIdx.x;
    const int wave = tid >> 6;
    const int lane = tid & 63;
    const int lane15 = lane & 15;
    const int quad = lane >> 4;
    const int wn = wave * 32;

    f32x4 acc[4][2];
#pragma unroll
    for (int i = 0; i < 4; i++)
#pragma unroll
        for (int j = 0; j < 2; j++)
            acc[i][j] = (f32x4){0.f, 0.f, 0.f, 0.f};

    const int srow = lane >> 2;        // 0..15
    const int scol = (lane & 3) * 8;

    const int arow = tid >> 2;
    const int acol = (tid & 3) * 8;
    const int gr = bm + arow;                 // global ctx row
    const int bIdx = gr >> 11;                // batch
    const int s = gr & (SS - 1);
    const int qt8 = s >> 8;                   // 256-row attn tile
    const int sq = s & (QT - 1);

    uint4 p0a, p1a, p0b, p1b;                 // {half0,half1} x {plane0,plane1}
    float l0, l1;

#define ALOAD(KT)                                                                 \
    {                                                                             \
        const int pb0_ = ((bIdx * NH + (KT)) * NQT + qt8) * 2;                    \
        const bf16* q0_ = po + (size_t)pb0_ * QT * HD + sq * HD;                  \
        const bf16* q1_ = po + (size_t)(pb0_ + 1) * QT * HD + sq * HD;            \
        p0a = *(const uint4*)(q0_ + acol);                                        \
        p0b = *(const uint4*)(q0_ + 32 + acol);                                   \
        p1a = *(const uint4*)(q1_ + acol);                                        \
        p1b = *(const uint4*)(q1_ + 32 + acol);                                   \
        l0 = pl[(size_t)pb0_ * QT + sq];                                          \
        l1 = pl[(size_t)(pb0_ + 1) * QT + sq];                                    \
    }

    ALOAD(0);

    for (int kt = 0; kt < NH; kt++) {         // 16 iterations, k0 = kt*64, h = kt
        __syncthreads();                      // prev readers done
        // ---- commit A (fused combine) ----
        {
            const float inv = 1.0f / fmaxf(l0 + l1, 1e-30f);
            const bf16* x0 = (const bf16*)&p0a; const bf16* y0 = (const bf16*)&p1a;
            const bf16* x1 = (const bf16*)&p0b; const bf16* y1 = (const bf16*)&p1b;
            bf16 o0[8], o1[8];
#pragma unroll
            for (int e = 0; e < 8; e++) {
                o0[e] = __float2bfloat16((__bfloat162float(x0[e]) + __bfloat162float(y0[e])) * inv);
                o1[e] = __float2bfloat16((__bfloat162float(x1[e]) + __bfloat162float(y1[e])) * inv);
            }
            *(uint4*)(As + 0 * 2048 + arow * 32 + acol) = *(const uint4*)o0;
            *(uint4*)(As + 1 * 2048 + arow * 32 + acol) = *(const uint4*)o1;
        }
        // ---- B glds16 staging ----
#pragma unroll
        for (int n = 0; n < 4; n++) {
            const int c = wave * 4 + n;
            const int plane = c >> 3;
            const int cc = c & 7;
            glds16(Wob + (size_t)(bn + cc * 16 + srow) * SIZE + kt * 64 + plane * 32 + scol,
                   Bs + c * 512);
        }
        __syncthreads();                      // drain ds_write + glds16

        if (kt + 1 < NH) ALOAD(kt + 1);       // prefetch flows under MFMAs

#pragma unroll
        for (int kk = 0; kk < 2; kk++) {
            frag16 a[4], b[2];
#pragma unroll
            for (int mi = 0; mi < 4; mi++)
                a[mi] = *(const frag16*)(As + kk * 2048 + (mi * 16 + lane15) * 32 + quad * 8);
#pragma unroll
            for (int ni = 0; ni < 2; ni++)
                b[ni] = *(const frag16*)(Bs + kk * 4096 + (wn + ni * 16 + lane15) * 32 + quad * 8);
#pragma unroll
            for (int mi = 0; mi < 4; mi++)
#pragma unroll
                for (int ni = 0; ni < 2; ni++)
                    acc[mi][ni] = __builtin_amdgcn_mfma_f32_16x16x32_bf16(
                        a[mi], b[ni], acc[mi][ni], 0, 0, 0);
        }
    }
#undef ALOAD

#pragma unroll
    for (int ni = 0; ni < 2; ni++) {
        const int col = bn + wn + ni * 16 + lane15;
        const float bv = bo[col];
#pragma unroll
        for (int mi = 0; mi < 4; mi++) {
            const int row = bm + mi * 16 + quad * 4;
#pragma unroll
            for (int r = 0; r < 4; r++)
                out[(size_t)(row + r) * SIZE + col] = acc[mi][ni][r] + bv;
        }
    }
}

extern "C" void kernel_launch(void* const* d_in, const int* in_sizes, int n_in,
                              void* d_out, int out_size, void* d_ws, size_t ws_size,
                              hipStream_t stream) {
    const float* q  = (const float*)d_in[0];
    const float* k  = (const float*)d_in[1];
    const float* v  = (const float*)d_in[2];
    const float* Wq = (const float*)d_in[3];
    const float* bq = (const float*)d_in[4];
    const float* Wk = (const float*)d_in[5];
    const float* bk = (const float*)d_in[6];
    const float* Wv = (const float*)d_in[7];
    const float* bv = (const float*)d_in[8];
    const float* Wo = (const float*)d_in[9];
    const float* bo = (const float*)d_in[10];
    float* out = (float*)d_out;

    // ws (bf16): Wb[4M] | qb | kb | vb | qh | kh | vt  (4.19M elems each)
    // aliases: po (8.39M) = qb+kb (dead after qkv); pl = Wq slot (dead after qkv)
    bf16* Wb  = (bf16*)d_ws;
    bf16* qb  = Wb + (size_t)4 * SIZE * SIZE;
    bf16* kb  = qb + (size_t)MROWS * SIZE;
    bf16* vb  = kb + (size_t)MROWS * SIZE;
    bf16* qh  = vb + (size_t)MROWS * SIZE;
    bf16* kh  = qh + (size_t)MROWS * SIZE;
    bf16* vt  = kh + (size_t)MROWS * SIZE;
    bf16* po  = qb;
    float* pl = (float*)Wb;

    cast_kernel<<<dim3(8192, 1, 1), 256, 0, stream>>>(
        Wq, Wk, Wv, Wo, q, k, v, Wb, qb, kb, vb);
    qkv_proj_kernel<<<dim3(768, 1, 1), 256, 0, stream>>>(
        qb, kb, vb, Wb, bq, bk, bv, qh, kh, vt);
    attn_kernel<<<dim3(512, 1, 1), 256, 0, stream>>>(qh, kh, vt, po, pl);
    out_proj_kernel<<<dim3(512, 1, 1), 256, 0, stream>>>(
        po, pl, Wb + (size_t)3 * SIZE * SIZE, bo, out);
}

// Round 10
// 248.020 us; speedup vs baseline: 1.0317x; 1.0227x over previous
//
#include <hip/hip_runtime.h>
#include <hip/hip_bf16.h>

#define SIZE 1024
#define NH 16
#define HD 64
#define BB 2
#define SS 2048
#define MROWS (BB * SS)  // 4096
#define QT 256           // attn q-tile (64 rows per wave)
#define NQT (SS / QT)    // 8 q-tiles per (b,h)
#define NKT ((SS / 2) / 64)  // 16 k-tiles per S-half

using bf16 = __hip_bfloat16;
using frag16 = __attribute__((ext_vector_type(8))) short;   // 8 bf16 (4 VGPRs)
using f32x4 = __attribute__((ext_vector_type(4))) float;    // 4 fp32 acc
using f32x16 = __attribute__((ext_vector_type(16))) float;  // 32x32 acc
typedef unsigned int u32;
typedef __attribute__((ext_vector_type(4))) unsigned int u32x4v;

// async global->LDS, 16B per lane; lds dest = wave-uniform base + lane*16 (m97/m104)
__device__ __forceinline__ void glds16(const bf16* g, bf16* l) {
    __builtin_amdgcn_global_load_lds(
        (const __attribute__((address_space(1))) u32*)g,
        (__attribute__((address_space(3))) u32*)l, 16, 0, 0);
}

__device__ __forceinline__ void cvt_store8(bf16* dst, const float* src) {
    float4 a = *(const float4*)src;
    float4 b = *(const float4*)(src + 4);
    bf16 t[8];
    t[0] = __float2bfloat16(a.x); t[1] = __float2bfloat16(a.y);
    t[2] = __float2bfloat16(a.z); t[3] = __float2bfloat16(a.w);
    t[4] = __float2bfloat16(b.x); t[5] = __float2bfloat16(b.y);
    t[6] = __float2bfloat16(b.z); t[7] = __float2bfloat16(b.w);
    *(uint4*)dst = *(const uint4*)t;
}

// ---------------------------------------------------------------------------
// fp32 -> bf16 cast, flat grid: 16M elems / 8 per thread. (Frozen.)
// ---------------------------------------------------------------------------
__global__ __launch_bounds__(256) void cast_kernel(
    const float* __restrict__ Wq, const float* __restrict__ Wk,
    const float* __restrict__ Wv, const float* __restrict__ Wo,
    const float* __restrict__ q, const float* __restrict__ k,
    const float* __restrict__ v,
    bf16* __restrict__ Wb, bf16* __restrict__ qb,
    bf16* __restrict__ kb, bf16* __restrict__ vb)
{
    const size_t WN = (size_t)SIZE * SIZE;          // 1<<20
    const size_t AN = (size_t)MROWS * SIZE;         // 1<<22
    const size_t e = ((size_t)blockIdx.x * 256 + threadIdx.x) * 8;
    if (e < 4 * WN) {
        const int which = (int)(e >> 20);
        const size_t off = e & (WN - 1);
        const float* s = (which == 0) ? Wq : (which == 1) ? Wk : (which == 2) ? Wv : Wo;
        cvt_store8(Wb + e, s + off);
    } else {
        const size_t a = e - 4 * WN;
        const int which = (int)(a >> 22);
        const size_t off = a & (AN - 1);
        const float* s = (which == 0) ? q : (which == 1) ? k : v;
        bf16* d = (which == 0) ? qb : (which == 1) ? kb : vb;
        cvt_store8(d + off, s + off);
    }
}

// ---------------------------------------------------------------------------
// qkv GEMM: 128x128 tile, BK=32, glds16 both operands, dbuf, 1 barrier/kt,
// XCD-swizzled (R7-proven). (Frozen.)
// ---------------------------------------------------------------------------
__device__ __forceinline__ void gemm_body(
    const bf16* __restrict__ X, const bf16* __restrict__ W,
    const float* __restrict__ bias, bf16* __restrict__ Y, float scale, bool vt_mode,
    int bm, int bn)
{
    __shared__ __align__(16) bf16 smem[16384];   // As[2][4096] | Bs[2][4096]; tr reuse
    bf16* As = smem;                             // buf b at As + b*4096
    bf16* Bs = smem + 8192;

    const int tid = threadIdx.x;
    const int wave = tid >> 6;
    const int lane = tid & 63;
    const int lane15 = lane & 15;
    const int quad = lane >> 4;
    const int wm = (wave & 1) * 64;
    const int wn = (wave >> 1) * 64;

    f32x4 acc[4][4];
#pragma unroll
    for (int i = 0; i < 4; i++)
#pragma unroll
        for (int j = 0; j < 4; j++)
            acc[i][j] = (f32x4){0.f, 0.f, 0.f, 0.f};

    const int srow = lane >> 2;        // 0..15 within 16-row chunk
    const int scol = (lane & 3) * 8;   // 0/8/16/24

#define STAGE(KT, BUF)                                                         \
    {                                                                          \
        _Pragma("unroll")                                                      \
        for (int n = 0; n < 2; n++) {                                          \
            const int c = wave * 2 + n;   /* chunk 0..7, 16 rows each */       \
            glds16(X + (size_t)(bm + c * 16 + srow) * SIZE + (KT) * 32 + scol, \
                   As + (BUF) * 4096 + c * 512);                               \
            glds16(W + (size_t)(bn + c * 16 + srow) * SIZE + (KT) * 32 + scol, \
                   Bs + (BUF) * 4096 + c * 512);                               \
        }                                                                      \
    }

    // prologue: tile 0 (latency exposed once)
    STAGE(0, 0);
    __syncthreads();

    for (int kt = 0; kt < SIZE / 32; kt++) {
        const int buf = kt & 1;
        if (kt + 1 < SIZE / 32) STAGE(kt + 1, buf ^ 1);   // prefetch -> other buffer
        __builtin_amdgcn_sched_barrier(0);                // pin prefetch before compute

        frag16 a[4], b[4];
#pragma unroll
        for (int mi = 0; mi < 4; mi++)
            a[mi] = *(const frag16*)(As + buf * 4096 + (wm + mi * 16 + lane15) * 32 + quad * 8);
#pragma unroll
        for (int ni = 0; ni < 4; ni++)
            b[ni] = *(const frag16*)(Bs + buf * 4096 + (wn + ni * 16 + lane15) * 32 + quad * 8);
#pragma unroll
        for (int mi = 0; mi < 4; mi++)
#pragma unroll
            for (int ni = 0; ni < 4; ni++)
                acc[mi][ni] = __builtin_amdgcn_mfma_f32_16x16x32_bf16(
                    a[mi], b[ni], acc[mi][ni], 0, 0, 0);

        __syncthreads();   // drains prefetch glds16 (vmcnt0) AFTER compute; buf^1 ready
    }
#undef STAGE

    if (!vt_mode) {
        // C/D layout col=lane&15, row=quad*4+reg (m89/m91)
#pragma unroll
        for (int ni = 0; ni < 4; ni++) {
            const int col = bn + wn + ni * 16 + lane15;
            const float bv = bias[col];
#pragma unroll
            for (int mi = 0; mi < 4; mi++) {
                const int row = bm + wm + mi * 16 + quad * 4;
#pragma unroll
                for (int r = 0; r < 4; r++)
                    Y[(size_t)(row + r) * SIZE + col] =
                        __float2bfloat16((acc[mi][ni][r] + bv) * scale);
            }
        }
    } else {
        // transpose epilogue -> vt[b][h][d][s], coalesced 16B stores
        bf16* tr = smem;                   // [64][136] = 8704 elems, fits
        const int bloc = bm >> 11;
        const int s0g = bm & (SS - 1);
#pragma unroll
        for (int p = 0; p < 2; p++) {
            __syncthreads();
            if ((wave >> 1) == p) {
#pragma unroll
                for (int ni = 0; ni < 4; ni++) {
                    const int colp = ni * 16 + lane15;
                    const float bv = bias[bn + p * 64 + colp];
#pragma unroll
                    for (int mi = 0; mi < 4; mi++) {
                        const int row = wm + mi * 16 + quad * 4;
#pragma unroll
                        for (int r = 0; r < 4; r++)
                            tr[colp * 136 + row + r] =
                                __float2bfloat16(acc[mi][ni][r] + bv);
                    }
                }
            }
            __syncthreads();
            const int colp = tid >> 2;
            const int gcol = bn + p * 64 + colp;
            const int hh = gcol >> 6, dd = gcol & (HD - 1);
            bf16* dst = (bf16*)Y + ((size_t)(bloc * NH + hh) * HD + dd) * SS
                        + s0g + (tid & 3) * 32;
            const bf16* src = tr + colp * 136 + (tid & 3) * 32;
#pragma unroll
            for (int j = 0; j < 4; j++)
                *(uint4*)(dst + j * 8) = *(const uint4*)(src + j * 8);
        }
    }
}

// 1-D grid of 768; bijective XCD swizzle (nwg=768, 768%8==0, chunk=96):
// work w = (f%8)*96 + f/8; decode x-fastest (8 col-tiles, 32 row-tiles, 3 z)
__global__ __launch_bounds__(256) void qkv_proj_kernel(
    const bf16* __restrict__ qb, const bf16* __restrict__ kb, const bf16* __restrict__ vb,
    const bf16* __restrict__ Wb,
    const float* __restrict__ bq, const float* __restrict__ bk, const float* __restrict__ bv,
    bf16* __restrict__ qh, bf16* __restrict__ kh, bf16* __restrict__ vt)
{
    const int f = blockIdx.x;
    const int w = (f & 7) * 96 + (f >> 3);
    const int z = w >> 8;             // /256 (blocks per z-slice)
    const int rem = w & 255;
    const int bn = (rem & 7) * 128;   // col tile (x-fastest within chunk)
    const int bm = (rem >> 3) * 128;  // row tile

    const bf16 *X, *W; const float* bi; bf16* Y; float sc; bool vm;
    if (z == 0)      { X = qb; W = Wb;                   bi = bq; Y = qh; sc = 0.125f; vm = false; }
    else if (z == 1) { X = kb; W = Wb + SIZE * SIZE;     bi = bk; Y = kh; sc = 1.0f;   vm = false; }
    else             { X = vb; W = Wb + 2 * SIZE * SIZE; bi = bv; Y = vt; sc = 1.0f;   vm = true;  }
    gemm_body(X, W, bi, Y, sc, vm, bm, bn);
}

// ---------------------------------------------------------------------------
// Flash attention, split-S, QT=256 (64 q-rows/wave), 32x32 MFMA path with
// IN-REGISTER P (T12): Ps LDS buffer deleted.
//   QK^T (swapped): c = mfma_32x32x16(K-frag, Q-frag) -> lane(q=lane&31,
//     t=lane>=32) holds P at keys {r+8s+4t} (C-layout m74).
//   P->PV A-frag: pack exp results with v_cvt_pk_bf16_f32 into w[s], then
//     (word_j, word_{2+j}) = permlane32_swap(w[2kk2][j], w[2kk2+1][j])
//     yields exactly the A-frag words (m214 v22 recipe).
//   l: f32 adds folded into exp pass + final shfl_xor(32) (replaces l-MFMA).
// K,V both LDS-staged (R9: destaging either costs; R7 pipeline kept: dbuf,
// ISSUE-early/COMMIT-late, 1 barrier/kt). XCD swizzle kept (FETCH 12.4MB).
// LDS 36,864 B. Removes 24 DS-ops + wave_barrier + ~3.1M conflict-cyc/dispatch.
// ---------------------------------------------------------------------------
__global__ __launch_bounds__(256) void attn_kernel(
    const bf16* __restrict__ qh, const bf16* __restrict__ kh,
    const bf16* __restrict__ vt, bf16* __restrict__ po, float* __restrict__ pl)
{
    __shared__ __align__(16) bf16 Ks[2][64][72];   // 18,432 B
    __shared__ __align__(16) bf16 Vs[2][64][72];   // 18,432 B

    const int tid = threadIdx.x;
    const int wave = tid >> 6;
    const int lane = tid & 63;
    const int L31 = lane & 31;
    const int t8 = (lane >> 5) * 8;   // 0 or 8: k-offset of this half-wave

    // XCD swizzle: w = xcd*64 + f/8 -> each XCD owns 4 (b,h) x 16 blocks;
    // K/V working set 2MB < 4MB L2/XCD.
    const int f = blockIdx.x;
    const int w = (f & 7) * 64 + (f >> 3);
    const int bh = w >> 4;            // 0..31
    const int within = w & 15;
    const int b = bh >> 4;            // BB=2, NH=16
    const int h = bh & 15;
    const int qt = within >> 1;
    const int sh = within & 1;
    const int q0 = qt * QT;

    const size_t baseq = (size_t)b * SS * SIZE + (size_t)h * HD;
    const size_t basev = (size_t)(b * NH + h) * HD * SS;
    const float LOG2E = 1.44269504088896340736f;
    const float OFF = 12.0f * LOG2E;

    // Q B-frags: aq[m2][kk]: Q[q = q0+wave*64+m2*32+L31][k = kk*16 + t8 + e]
    frag16 aq[2][4];
#pragma unroll
    for (int m2 = 0; m2 < 2; m2++) {
        const bf16* qp = qh + baseq
            + (size_t)(q0 + wave * 64 + m2 * 32 + L31) * SIZE + t8;
#pragma unroll
        for (int kk = 0; kk < 4; kk++)
            aq[m2][kk] = *(const frag16*)(qp + kk * 16);
    }

    f32x16 ofrag[2][2];               // [m2][d2]: O rows=q-map, col=d=lane31
#pragma unroll
    for (int m2 = 0; m2 < 2; m2++)
#pragma unroll
        for (int d2 = 0; d2 < 2; d2++)
#pragma unroll
            for (int r = 0; r < 16; r++)
                ofrag[m2][d2][r] = 0.f;
    float lsc[2] = {0.f, 0.f};        // per-lane partial l (own 16 keys/kt)

    const int sr = tid >> 3;          // 0..31 (staging rows)
    const int sc = (tid & 7) * 8;

    uint4 rk0, rk1, rv0, rv1;         // tile in flight
#define ISSUE(KT)                                                              \
    {                                                                          \
        const int s0_ = sh * (SS / 2) + (KT) * 64;                             \
        rk0 = *(const uint4*)(kh + baseq + (size_t)(s0_ + sr) * SIZE + sc);    \
        rk1 = *(const uint4*)(kh + baseq + (size_t)(s0_ + sr + 32) * SIZE + sc);\
        rv0 = *(const uint4*)(vt + basev + (size_t)sr * SS + s0_ + sc);        \
        rv1 = *(const uint4*)(vt + basev + (size_t)(sr + 32) * SS + s0_ + sc); \
    }
#define COMMIT(BUF)                                                            \
    {                                                                          \
        *(uint4*)&Ks[BUF][sr][sc] = rk0; *(uint4*)&Ks[BUF][sr + 32][sc] = rk1; \
        *(uint4*)&Vs[BUF][sr][sc] = rv0; *(uint4*)&Vs[BUF][sr + 32][sc] = rv1; \
    }

    ISSUE(0); COMMIT(0);
    __syncthreads();

    for (int kt = 0; kt < NKT; kt++) {
        const int buf = kt & 1;
        if (kt + 1 < NKT) ISSUE(kt + 1);          // prefetch in flight
        __builtin_amdgcn_sched_barrier(0);        // pin loads before compute

#pragma unroll
        for (int n2 = 0; n2 < 2; n2++) {
            // K A-frags: K[key = n2*32+L31][k = kk*16 + t8 + e]
            frag16 kfr[4];
#pragma unroll
            for (int kk = 0; kk < 4; kk++)
                kfr[kk] = *(const frag16*)&Ks[buf][n2 * 32 + L31][kk * 16 + t8];

            frag16 pa[2][2];          // [m2][kk2] PV A-frags (in-register P)
#pragma unroll
            for (int m2 = 0; m2 < 2; m2++) {
                f32x16 c;
#pragma unroll
                for (int r = 0; r < 16; r++) c[r] = 0.f;
#pragma unroll
                for (int kk = 0; kk < 4; kk++)
                    c = __builtin_amdgcn_mfma_f32_32x32x16_bf16(
                        kfr[kk], aq[m2][kk], c, 0, 0, 0);
                // c[reg] = S[key = n2*32 + (reg&3)+8*(reg>>2)+4t][q = m2-tile L31]
                float p[16];
                float s = 0.f;
#pragma unroll
                for (int r = 0; r < 16; r++) {
                    p[r] = exp2f(c[r] * LOG2E - OFF);
                    s += p[r];
                }
                lsc[m2] += s;
                // pack: wv[s4][j] = bf16x2(p[4s+2j], p[4s+2j+1]) = keys (8s+4t+2j, +1)
                u32 wv[4][2];
#pragma unroll
                for (int s4 = 0; s4 < 4; s4++)
#pragma unroll
                    for (int j = 0; j < 2; j++)
                        asm("v_cvt_pk_bf16_f32 %0, %1, %2"
                            : "=v"(wv[s4][j])
                            : "v"(p[s4 * 4 + 2 * j]), "v"(p[s4 * 4 + 2 * j + 1]));
                // swap: A-frag(kk2) words: (wd[j], wd[2+j]) = swap(wv[2kk2][j], wv[2kk2+1][j])
#pragma unroll
                for (int kk2 = 0; kk2 < 2; kk2++) {
                    u32x4v wd;
#pragma unroll
                    for (int j = 0; j < 2; j++) {
                        auto rr = __builtin_amdgcn_permlane32_swap(
                            wv[2 * kk2][j], wv[2 * kk2 + 1][j], false, false);
                        wd[j] = rr[0];
                        wd[2 + j] = rr[1];
                    }
                    pa[m2][kk2] = __builtin_bit_cast(frag16, wd);
                }
            }

            __builtin_amdgcn_s_setprio(1);
            // ---- O += P V: mfma(A=P[q][k], B=V[d][k]) ----
#pragma unroll
            for (int kk2 = 0; kk2 < 2; kk2++)
#pragma unroll
                for (int d2 = 0; d2 < 2; d2++) {
                    frag16 vfr = *(const frag16*)
                        &Vs[buf][d2 * 32 + L31][n2 * 32 + kk2 * 16 + t8];
#pragma unroll
                    for (int m2 = 0; m2 < 2; m2++)
                        ofrag[m2][d2] = __builtin_amdgcn_mfma_f32_32x32x16_bf16(
                            pa[m2][kk2], vfr, ofrag[m2][d2], 0, 0, 0);
                }
            __builtin_amdgcn_s_setprio(0);
        }

        if (kt + 1 < NKT) {
            COMMIT(buf ^ 1);                      // prefetch landed by now
            __syncthreads();
        }
    }
#undef ISSUE
#undef COMMIT

    // ---- partial outputs (un-normalized O + row sums) ----
    const int pb = ((b * NH + h) * NQT + qt) * 2 + sh;
    {
        float* plp = pl + (size_t)pb * QT;
#pragma unroll
        for (int m2 = 0; m2 < 2; m2++) {
            const float ltot = lsc[m2] + __shfl_xor(lsc[m2], 32);
            if (lane < 32)
                plp[wave * 64 + m2 * 32 + L31] = ltot;
        }
    }
    bf16* pop = po + (size_t)pb * QT * HD;
    const int t4 = (lane >> 5) * 4;
#pragma unroll
    for (int m2 = 0; m2 < 2; m2++)
#pragma unroll
        for (int d2 = 0; d2 < 2; d2++)
#pragma unroll
            for (int r = 0; r < 16; r++) {
                const int row = wave * 64 + m2 * 32 + (r & 3) + 8 * (r >> 2) + t4;
                pop[(size_t)row * HD + d2 * 32 + L31] =
                    __float2bfloat16(ofrag[m2][d2][r]);
            }
}

// ---------------------------------------------------------------------------
// Output projection with FUSED combine, XCD-swizzled (R7-proven). (Frozen.)
// ---------------------------------------------------------------------------
__global__ __launch_bounds__(256) void out_proj_kernel(
    const bf16* __restrict__ po, const float* __restrict__ pl,
    const bf16* __restrict__ Wob, const float* __restrict__ bo,
    float* __restrict__ out)
{
    __shared__ __align__(16) bf16 As[2 * 64 * 32];    // [2 planes][64][32]
    __shared__ __align__(16) bf16 Bs[2 * 128 * 32];   // [2 planes][128][32]

    const int f = blockIdx.x;
    const int w = (f & 7) * 64 + (f >> 3);    // bijective, nwg=512
    const int bn = (w & 7) * 128;             // col tile (x-fastest)
    const int bm = (w >> 3) * 64;             // row tile

    const int tid = threadIdx.x;
    const int wave = tid >> 6;
    const int lane = tid & 63;
    const int lane15 = lane & 15;
    const int quad = lane >> 4;
    const int wn = wave * 32;

    f32x4 acc[4][2];
#pragma unroll
    for (int i = 0; i < 4; i++)
#pragma unroll
        for (int j = 0; j < 2; j++)
            acc[i][j] = (f32x4){0.f, 0.f, 0.f, 0.f};

    const int srow = lane >> 2;        // 0..15
    const int scol = (lane & 3) * 8;

    const int arow = tid >> 2;
    const int acol = (tid & 3) * 8;
    const int gr = bm + arow;                 // global ctx row
    const int bIdx = gr >> 11;                // batch
    const int s = gr & (SS - 1);
    const int qt8 = s >> 8;                   // 256-row attn tile
    const int sq = s & (QT - 1);

    uint4 p0a, p1a, p0b, p1b;                 // {half0,half1} x {plane0,plane1}
    float l0, l1;

#define ALOAD(KT)                                                                 \
    {                                                                             \
        const int pb0_ = ((bIdx * NH + (KT)) * NQT + qt8) * 2;                    \
        const bf16* q0_ = po + (size_t)pb0_ * QT * HD + sq * HD;                  \
        const bf16* q1_ = po + (size_t)(pb0_ + 1) * QT * HD + sq * HD;            \
        p0a = *(const uint4*)(q0_ + acol);                                        \
        p0b = *(const uint4*)(q0_ + 32 + acol);                                   \
        p1a = *(const uint4*)(q1_ + acol);                                        \
        p1b = *(const uint4*)(q1_ + 32 + acol);                                   \
        l0 = pl[(size_t)pb0_ * QT + sq];                                          \
        l1 = pl[(size_t)(pb0_ + 1) * QT + sq];                                    \
    }

    ALOAD(0);

    for (int kt = 0; kt < NH; kt++) {         // 16 iterations, k0 = kt*64, h = kt
        __syncthreads();                      // prev readers done
        // ---- commit A (fused combine) ----
        {
            const float inv = 1.0f / fmaxf(l0 + l1, 1e-30f);
            const bf16* x0 = (const bf16*)&p0a; const bf16* y0 = (const bf16*)&p1a;
            const bf16* x1 = (const bf16*)&p0b; const bf16* y1 = (const bf16*)&p1b;
            bf16 o0[8], o1[8];
#pragma unroll
            for (int e = 0; e < 8; e++) {
                o0[e] = __float2bfloat16((__bfloat162float(x0[e]) + __bfloat162float(y0[e])) * inv);
                o1[e] = __float2bfloat16((__bfloat162float(x1[e]) + __bfloat162float(y1[e])) * inv);
            }
            *(uint4*)(As + 0 * 2048 + arow * 32 + acol) = *(const uint4*)o0;
            *(uint4*)(As + 1 * 2048 + arow * 32 + acol) = *(const uint4*)o1;
        }
        // ---- B glds16 staging ----
#pragma unroll
        for (int n = 0; n < 4; n++) {
            const int c = wave * 4 + n;
            const int plane = c >> 3;
            const int cc = c & 7;
            glds16(Wob + (size_t)(bn + cc * 16 + srow) * SIZE + kt * 64 + plane * 32 + scol,
                   Bs + c * 512);
        }
        __syncthreads();                      // drain ds_write + glds16

        if (kt + 1 < NH) ALOAD(kt + 1);       // prefetch flows under MFMAs

#pragma unroll
        for (int kk = 0; kk < 2; kk++) {
            frag16 a[4], b[2];
#pragma unroll
            for (int mi = 0; mi < 4; mi++)
                a[mi] = *(const frag16*)(As + kk * 2048 + (mi * 16 + lane15) * 32 + quad * 8);
#pragma unroll
            for (int ni = 0; ni < 2; ni++)
                b[ni] = *(const frag16*)(Bs + kk * 4096 + (wn + ni * 16 + lane15) * 32 + quad * 8);
#pragma unroll
            for (int mi = 0; mi < 4; mi++)
#pragma unroll
                for (int ni = 0; ni < 2; ni++)
                    acc[mi][ni] = __builtin_amdgcn_mfma_f32_16x16x32_bf16(
                        a[mi], b[ni], acc[mi][ni], 0, 0, 0);
        }
    }
#undef ALOAD

#pragma unroll
    for (int ni = 0; ni < 2; ni++) {
        const int col = bn + wn + ni * 16 + lane15;
        const float bv = bo[col];
#pragma unroll
        for (int mi = 0; mi < 4; mi++) {
            const int row = bm + mi * 16 + quad * 4;
#pragma unroll
            for (int r = 0; r < 4; r++)
                out[(size_t)(row + r) * SIZE + col] = acc[mi][ni][r] + bv;
        }
    }
}

extern "C" void kernel_launch(void* const* d_in, const int* in_sizes, int n_in,
                              void* d_out, int out_size, void* d_ws, size_t ws_size,
                              hipStream_t stream) {
    const float* q  = (const float*)d_in[0];
    const float* k  = (const float*)d_in[1];
    const float* v  = (const float*)d_in[2];
    const float* Wq = (const float*)d_in[3];
    const float* bq = (const float*)d_in[4];
    const float* Wk = (const float*)d_in[5];
    const float* bk = (const float*)d_in[6];
    const float* Wv = (const float*)d_in[7];
    const float* bv = (const float*)d_in[8];
    const float* Wo = (const float*)d_in[9];
    const float* bo = (const float*)d_in[10];
    float* out = (float*)d_out;

    // ws (bf16): Wb[4M] | qb | kb | vb | qh | kh | vt  (4.19M elems each)
    // aliases: po (8.39M) = qb+kb (dead after qkv); pl = Wq slot (dead after qkv)
    bf16* Wb  = (bf16*)d_ws;
    bf16* qb  = Wb + (size_t)4 * SIZE * SIZE;
    bf16* kb  = qb + (size_t)MROWS * SIZE;
    bf16* vb  = kb + (size_t)MROWS * SIZE;
    bf16* qh  = vb + (size_t)MROWS * SIZE;
    bf16* kh  = qh + (size_t)MROWS * SIZE;
    bf16* vt  = kh + (size_t)MROWS * SIZE;
    bf16* po  = qb;
    float* pl = (float*)Wb;

    cast_kernel<<<dim3(8192, 1, 1), 256, 0, stream>>>(
        Wq, Wk, Wv, Wo, q, k, v, Wb, qb, kb, vb);
    qkv_proj_kernel<<<dim3(768, 1, 1), 256, 0, stream>>>(
        qb, kb, vb, Wb, bq, bk, bv, qh, kh, vt);
    attn_kernel<<<dim3(512, 1, 1), 256, 0, stream>>>(qh, kh, vt, po, pl);
    out_proj_kernel<<<dim3(512, 1, 1), 256, 0, stream>>>(
        po, pl, Wb + (size_t)3 * SIZE * SIZE, bo, out);
}

// Round 11
// 244.222 us; speedup vs baseline: 1.0478x; 1.0155x over previous
//
#include <hip/hip_runtime.h>
#include <hip/hip_bf16.h>

#define SIZE 1024
#define NH 16
#define HD 64
#define BB 2
#define SS 2048
#define MROWS (BB * SS)  // 4096
#define QT 128           // attn q-tile (32 rows per wave; R11: 4 blocks/CU)
#define NQT (SS / QT)    // 16 q-tiles per (b,h)
#define NKT ((SS / 2) / 64)  // 16 k-tiles per S-half

using bf16 = __hip_bfloat16;
using frag16 = __attribute__((ext_vector_type(8))) short;   // 8 bf16 (4 VGPRs)
using f32x4 = __attribute__((ext_vector_type(4))) float;    // 4 fp32 acc
using f32x16 = __attribute__((ext_vector_type(16))) float;  // 32x32 acc
typedef unsigned int u32;
typedef __attribute__((ext_vector_type(4))) unsigned int u32x4v;

// async global->LDS, 16B per lane; lds dest = wave-uniform base + lane*16 (m97/m104)
__device__ __forceinline__ void glds16(const bf16* g, bf16* l) {
    __builtin_amdgcn_global_load_lds(
        (const __attribute__((address_space(1))) u32*)g,
        (__attribute__((address_space(3))) u32*)l, 16, 0, 0);
}

__device__ __forceinline__ void cvt_store8(bf16* dst, const float* src) {
    float4 a = *(const float4*)src;
    float4 b = *(const float4*)(src + 4);
    bf16 t[8];
    t[0] = __float2bfloat16(a.x); t[1] = __float2bfloat16(a.y);
    t[2] = __float2bfloat16(a.z); t[3] = __float2bfloat16(a.w);
    t[4] = __float2bfloat16(b.x); t[5] = __float2bfloat16(b.y);
    t[6] = __float2bfloat16(b.z); t[7] = __float2bfloat16(b.w);
    *(uint4*)dst = *(const uint4*)t;
}

// ---------------------------------------------------------------------------
// fp32 -> bf16 cast, flat grid: 16M elems / 8 per thread. (Frozen.)
// ---------------------------------------------------------------------------
__global__ __launch_bounds__(256) void cast_kernel(
    const float* __restrict__ Wq, const float* __restrict__ Wk,
    const float* __restrict__ Wv, const float* __restrict__ Wo,
    const float* __restrict__ q, const float* __restrict__ k,
    const float* __restrict__ v,
    bf16* __restrict__ Wb, bf16* __restrict__ qb,
    bf16* __restrict__ kb, bf16* __restrict__ vb)
{
    const size_t WN = (size_t)SIZE * SIZE;          // 1<<20
    const size_t AN = (size_t)MROWS * SIZE;         // 1<<22
    const size_t e = ((size_t)blockIdx.x * 256 + threadIdx.x) * 8;
    if (e < 4 * WN) {
        const int which = (int)(e >> 20);
        const size_t off = e & (WN - 1);
        const float* s = (which == 0) ? Wq : (which == 1) ? Wk : (which == 2) ? Wv : Wo;
        cvt_store8(Wb + e, s + off);
    } else {
        const size_t a = e - 4 * WN;
        const int which = (int)(a >> 22);
        const size_t off = a & (AN - 1);
        const float* s = (which == 0) ? q : (which == 1) ? k : v;
        bf16* d = (which == 0) ? qb : (which == 1) ? kb : vb;
        cvt_store8(d + off, s + off);
    }
}

// ---------------------------------------------------------------------------
// qkv GEMM: 128x128 tile, BK=32, glds16 both operands, dbuf, 1 barrier/kt,
// XCD-swizzled (R7-proven). (Frozen.)
// ---------------------------------------------------------------------------
__device__ __forceinline__ void gemm_body(
    const bf16* __restrict__ X, const bf16* __restrict__ W,
    const float* __restrict__ bias, bf16* __restrict__ Y, float scale, bool vt_mode,
    int bm, int bn)
{
    __shared__ __align__(16) bf16 smem[16384];   // As[2][4096] | Bs[2][4096]; tr reuse
    bf16* As = smem;                             // buf b at As + b*4096
    bf16* Bs = smem + 8192;

    const int tid = threadIdx.x;
    const int wave = tid >> 6;
    const int lane = tid & 63;
    const int lane15 = lane & 15;
    const int quad = lane >> 4;
    const int wm = (wave & 1) * 64;
    const int wn = (wave >> 1) * 64;

    f32x4 acc[4][4];
#pragma unroll
    for (int i = 0; i < 4; i++)
#pragma unroll
        for (int j = 0; j < 4; j++)
            acc[i][j] = (f32x4){0.f, 0.f, 0.f, 0.f};

    const int srow = lane >> 2;        // 0..15 within 16-row chunk
    const int scol = (lane & 3) * 8;   // 0/8/16/24

#define STAGE(KT, BUF)                                                         \
    {                                                                          \
        _Pragma("unroll")                                                      \
        for (int n = 0; n < 2; n++) {                                          \
            const int c = wave * 2 + n;   /* chunk 0..7, 16 rows each */       \
            glds16(X + (size_t)(bm + c * 16 + srow) * SIZE + (KT) * 32 + scol, \
                   As + (BUF) * 4096 + c * 512);                               \
            glds16(W + (size_t)(bn + c * 16 + srow) * SIZE + (KT) * 32 + scol, \
                   Bs + (BUF) * 4096 + c * 512);                               \
        }                                                                      \
    }

    // prologue: tile 0 (latency exposed once)
    STAGE(0, 0);
    __syncthreads();

    for (int kt = 0; kt < SIZE / 32; kt++) {
        const int buf = kt & 1;
        if (kt + 1 < SIZE / 32) STAGE(kt + 1, buf ^ 1);   // prefetch -> other buffer
        __builtin_amdgcn_sched_barrier(0);                // pin prefetch before compute

        frag16 a[4], b[4];
#pragma unroll
        for (int mi = 0; mi < 4; mi++)
            a[mi] = *(const frag16*)(As + buf * 4096 + (wm + mi * 16 + lane15) * 32 + quad * 8);
#pragma unroll
        for (int ni = 0; ni < 4; ni++)
            b[ni] = *(const frag16*)(Bs + buf * 4096 + (wn + ni * 16 + lane15) * 32 + quad * 8);
#pragma unroll
        for (int mi = 0; mi < 4; mi++)
#pragma unroll
            for (int ni = 0; ni < 4; ni++)
                acc[mi][ni] = __builtin_amdgcn_mfma_f32_16x16x32_bf16(
                    a[mi], b[ni], acc[mi][ni], 0, 0, 0);

        __syncthreads();   // drains prefetch glds16 (vmcnt0) AFTER compute; buf^1 ready
    }
#undef STAGE

    if (!vt_mode) {
        // C/D layout col=lane&15, row=quad*4+reg (m89/m91)
#pragma unroll
        for (int ni = 0; ni < 4; ni++) {
            const int col = bn + wn + ni * 16 + lane15;
            const float bv = bias[col];
#pragma unroll
            for (int mi = 0; mi < 4; mi++) {
                const int row = bm + wm + mi * 16 + quad * 4;
#pragma unroll
                for (int r = 0; r < 4; r++)
                    Y[(size_t)(row + r) * SIZE + col] =
                        __float2bfloat16((acc[mi][ni][r] + bv) * scale);
            }
        }
    } else {
        // transpose epilogue -> vt[b][h][d][s], coalesced 16B stores
        bf16* tr = smem;                   // [64][136] = 8704 elems, fits
        const int bloc = bm >> 11;
        const int s0g = bm & (SS - 1);
#pragma unroll
        for (int p = 0; p < 2; p++) {
            __syncthreads();
            if ((wave >> 1) == p) {
#pragma unroll
                for (int ni = 0; ni < 4; ni++) {
                    const int colp = ni * 16 + lane15;
                    const float bv = bias[bn + p * 64 + colp];
#pragma unroll
                    for (int mi = 0; mi < 4; mi++) {
                        const int row = wm + mi * 16 + quad * 4;
#pragma unroll
                        for (int r = 0; r < 4; r++)
                            tr[colp * 136 + row + r] =
                                __float2bfloat16(acc[mi][ni][r] + bv);
                    }
                }
            }
            __syncthreads();
            const int colp = tid >> 2;
            const int gcol = bn + p * 64 + colp;
            const int hh = gcol >> 6, dd = gcol & (HD - 1);
            bf16* dst = (bf16*)Y + ((size_t)(bloc * NH + hh) * HD + dd) * SS
                        + s0g + (tid & 3) * 32;
            const bf16* src = tr + colp * 136 + (tid & 3) * 32;
#pragma unroll
            for (int j = 0; j < 4; j++)
                *(uint4*)(dst + j * 8) = *(const uint4*)(src + j * 8);
        }
    }
}

// 1-D grid of 768; bijective XCD swizzle (nwg=768, 768%8==0, chunk=96):
// work w = (f%8)*96 + f/8; decode x-fastest (8 col-tiles, 32 row-tiles, 3 z)
__global__ __launch_bounds__(256) void qkv_proj_kernel(
    const bf16* __restrict__ qb, const bf16* __restrict__ kb, const bf16* __restrict__ vb,
    const bf16* __restrict__ Wb,
    const float* __restrict__ bq, const float* __restrict__ bk, const float* __restrict__ bv,
    bf16* __restrict__ qh, bf16* __restrict__ kh, bf16* __restrict__ vt)
{
    const int f = blockIdx.x;
    const int w = (f & 7) * 96 + (f >> 3);
    const int z = w >> 8;             // /256 (blocks per z-slice)
    const int rem = w & 255;
    const int bn = (rem & 7) * 128;   // col tile (x-fastest within chunk)
    const int bm = (rem >> 3) * 128;  // row tile

    const bf16 *X, *W; const float* bi; bf16* Y; float sc; bool vm;
    if (z == 0)      { X = qb; W = Wb;                   bi = bq; Y = qh; sc = 0.125f; vm = false; }
    else if (z == 1) { X = kb; W = Wb + SIZE * SIZE;     bi = bk; Y = kh; sc = 1.0f;   vm = false; }
    else             { X = vb; W = Wb + 2 * SIZE * SIZE; bi = bv; Y = vt; sc = 1.0f;   vm = true;  }
    gemm_body(X, W, bi, Y, sc, vm, bm, bn);
}

// ---------------------------------------------------------------------------
// Flash attention, split-S, QT=128 (32 q-rows/wave), 32x32 MFMA, in-register
// P (T12, R10-proven: conflicts = 0, layout verified). R11 change: ONLY the
// occupancy. R10 ran grid 512 = 2 blocks/CU (17% occ) with VALUBusy 61% --
// the exp/pack/PV chain was latency-exposed at 2 waves/SIMD. Halving the
// q-tile doubles the grid to 1024 = 4 blocks/CU (LDS 4x36.9=147.5<160KB,
// launch_bounds(256,4) caps VGPR at 128; per-wave state is ~half of R10's).
// K,V LDS-staged dbuf, 1 barrier/kt; XCD swizzle (4 (b,h)/XCD) kept.
// ---------------------------------------------------------------------------
__global__ __launch_bounds__(256, 4) void attn_kernel(
    const bf16* __restrict__ qh, const bf16* __restrict__ kh,
    const bf16* __restrict__ vt, bf16* __restrict__ po, float* __restrict__ pl)
{
    __shared__ __align__(16) bf16 Ks[2][64][72];   // 18,432 B
    __shared__ __align__(16) bf16 Vs[2][64][72];   // 18,432 B

    const int tid = threadIdx.x;
    const int wave = tid >> 6;
    const int lane = tid & 63;
    const int L31 = lane & 31;
    const int t8 = (lane >> 5) * 8;   // 0 or 8: k-offset of this half-wave

    // XCD swizzle: nwg=1024, chunk=128 -> each XCD owns 4 (b,h) x 32 blocks;
    // K/V working set 4 x 1MB = 4MB L2/XCD.
    const int f = blockIdx.x;
    const int w = (f & 7) * 128 + (f >> 3);
    const int bh = w >> 5;            // 0..31
    const int within = w & 31;
    const int b = bh >> 4;            // BB=2, NH=16
    const int h = bh & 15;
    const int qt = within >> 1;       // 0..15
    const int sh = within & 1;
    const int q0 = qt * QT;

    const size_t baseq = (size_t)b * SS * SIZE + (size_t)h * HD;
    const size_t basev = (size_t)(b * NH + h) * HD * SS;
    const float LOG2E = 1.44269504088896340736f;
    const float OFF = 12.0f * LOG2E;

    // Q B-frags: aq[kk]: Q[q = q0+wave*32+L31][k = kk*16 + t8 + e]
    frag16 aq[4];
    {
        const bf16* qp = qh + baseq + (size_t)(q0 + wave * 32 + L31) * SIZE + t8;
#pragma unroll
        for (int kk = 0; kk < 4; kk++)
            aq[kk] = *(const frag16*)(qp + kk * 16);
    }

    f32x16 ofrag[2];                  // [d2]: O rows=q-map, col=d=lane31
#pragma unroll
    for (int d2 = 0; d2 < 2; d2++)
#pragma unroll
        for (int r = 0; r < 16; r++)
            ofrag[d2][r] = 0.f;
    float lsc = 0.f;                  // per-lane partial l (own 16 keys/kt)

    const int sr = tid >> 3;          // 0..31 (staging rows)
    const int sc = (tid & 7) * 8;

    uint4 rk0, rk1, rv0, rv1;         // tile in flight
#define ISSUE(KT)                                                              \
    {                                                                          \
        const int s0_ = sh * (SS / 2) + (KT) * 64;                             \
        rk0 = *(const uint4*)(kh + baseq + (size_t)(s0_ + sr) * SIZE + sc);    \
        rk1 = *(const uint4*)(kh + baseq + (size_t)(s0_ + sr + 32) * SIZE + sc);\
        rv0 = *(const uint4*)(vt + basev + (size_t)sr * SS + s0_ + sc);        \
        rv1 = *(const uint4*)(vt + basev + (size_t)(sr + 32) * SS + s0_ + sc); \
    }
#define COMMIT(BUF)                                                            \
    {                                                                          \
        *(uint4*)&Ks[BUF][sr][sc] = rk0; *(uint4*)&Ks[BUF][sr + 32][sc] = rk1; \
        *(uint4*)&Vs[BUF][sr][sc] = rv0; *(uint4*)&Vs[BUF][sr + 32][sc] = rv1; \
    }

    ISSUE(0); COMMIT(0);
    __syncthreads();

    for (int kt = 0; kt < NKT; kt++) {
        const int buf = kt & 1;
        if (kt + 1 < NKT) ISSUE(kt + 1);          // prefetch in flight
        __builtin_amdgcn_sched_barrier(0);        // pin loads before compute

#pragma unroll
        for (int n2 = 0; n2 < 2; n2++) {
            // K A-frags: K[key = n2*32+L31][k = kk*16 + t8 + e]
            frag16 kfr[4];
#pragma unroll
            for (int kk = 0; kk < 4; kk++)
                kfr[kk] = *(const frag16*)&Ks[buf][n2 * 32 + L31][kk * 16 + t8];

            // ---- S^T = K Q^T (swapped): lane(q=L31, t=lane>=32) ----
            f32x16 c;
#pragma unroll
            for (int r = 0; r < 16; r++) c[r] = 0.f;
#pragma unroll
            for (int kk = 0; kk < 4; kk++)
                c = __builtin_amdgcn_mfma_f32_32x32x16_bf16(
                    kfr[kk], aq[kk], c, 0, 0, 0);
            // c[reg] = S[key = n2*32 + (reg&3)+8*(reg>>2)+4t][q = L31]
            float p[16];
            float s = 0.f;
#pragma unroll
            for (int r = 0; r < 16; r++) {
                p[r] = exp2f(c[r] * LOG2E - OFF);
                s += p[r];
            }
            lsc += s;
            // pack: wv[s4][j] = bf16x2(p[4s+2j], p[4s+2j+1]) = keys (8s+4t+2j, +1)
            u32 wv[4][2];
#pragma unroll
            for (int s4 = 0; s4 < 4; s4++)
#pragma unroll
                for (int j = 0; j < 2; j++)
                    asm("v_cvt_pk_bf16_f32 %0, %1, %2"
                        : "=v"(wv[s4][j])
                        : "v"(p[s4 * 4 + 2 * j]), "v"(p[s4 * 4 + 2 * j + 1]));
            // swap: A-frag(kk2) words: (wd[j], wd[2+j]) = swap(wv[2kk2][j], wv[2kk2+1][j])
            frag16 pa[2];
#pragma unroll
            for (int kk2 = 0; kk2 < 2; kk2++) {
                u32x4v wd;
#pragma unroll
                for (int j = 0; j < 2; j++) {
                    auto rr = __builtin_amdgcn_permlane32_swap(
                        wv[2 * kk2][j], wv[2 * kk2 + 1][j], false, false);
                    wd[j] = rr[0];
                    wd[2 + j] = rr[1];
                }
                pa[kk2] = __builtin_bit_cast(frag16, wd);
            }

            __builtin_amdgcn_s_setprio(1);
            // ---- O += P V: mfma(A=P[q][k], B=V[d][k]) ----
#pragma unroll
            for (int kk2 = 0; kk2 < 2; kk2++)
#pragma unroll
                for (int d2 = 0; d2 < 2; d2++) {
                    frag16 vfr = *(const frag16*)
                        &Vs[buf][d2 * 32 + L31][n2 * 32 + kk2 * 16 + t8];
                    ofrag[d2] = __builtin_amdgcn_mfma_f32_32x32x16_bf16(
                        pa[kk2], vfr, ofrag[d2], 0, 0, 0);
                }
            __builtin_amdgcn_s_setprio(0);
        }

        if (kt + 1 < NKT) {
            COMMIT(buf ^ 1);                      // prefetch landed by now
            __syncthreads();
        }
    }
#undef ISSUE
#undef COMMIT

    // ---- partial outputs (un-normalized O + row sums) ----
    const int pb = ((b * NH + h) * NQT + qt) * 2 + sh;
    {
        const float ltot = lsc + __shfl_xor(lsc, 32);
        if (lane < 32)
            pl[(size_t)pb * QT + wave * 32 + L31] = ltot;
    }
    bf16* pop = po + (size_t)pb * QT * HD;
    const int t4 = (lane >> 5) * 4;
#pragma unroll
    for (int d2 = 0; d2 < 2; d2++)
#pragma unroll
        for (int r = 0; r < 16; r++) {
            const int row = wave * 32 + (r & 3) + 8 * (r >> 2) + t4;
            pop[(size_t)row * HD + d2 * 32 + L31] =
                __float2bfloat16(ofrag[d2][r]);
        }
}

// ---------------------------------------------------------------------------
// Output projection with FUSED combine, XCD-swizzled (R7-proven).
// Updated for QT=128 partials: qt8 = s>>7, NQT=16. Otherwise frozen.
// ---------------------------------------------------------------------------
__global__ __launch_bounds__(256) void out_proj_kernel(
    const bf16* __restrict__ po, const float* __restrict__ pl,
    const bf16* __restrict__ Wob, const float* __restrict__ bo,
    float* __restrict__ out)
{
    __shared__ __align__(16) bf16 As[2 * 64 * 32];    // [2 planes][64][32]
    __shared__ __align__(16) bf16 Bs[2 * 128 * 32];   // [2 planes][128][32]

    const int f = blockIdx.x;
    const int w = (f & 7) * 64 + (f >> 3);    // bijective, nwg=512
    const int bn = (w & 7) * 128;             // col tile (x-fastest)
    const int bm = (w >> 3) * 64;             // row tile

    const int tid = threadIdx.x;
    const int wave = tid >> 6;
    const int lane = tid & 63;
    const int lane15 = lane & 15;
    const int quad = lane >> 4;
    const int wn = wave * 32;

    f32x4 acc[4][2];
#pragma unroll
    for (int i = 0; i < 4; i++)
#pragma unroll
        for (int j = 0; j < 2; j++)
            acc[i][j] = (f32x4){0.f, 0.f, 0.f, 0.f};

    const int srow = lane >> 2;        // 0..15
    const int scol = (lane & 3) * 8;

    const int arow = tid >> 2;
    const int acol = (tid & 3) * 8;
    const int gr = bm + arow;                 // global ctx row
    const int bIdx = gr >> 11;                // batch
    const int s = gr & (SS - 1);
    const int qt8 = s >> 7;                   // 128-row attn tile (QT=128)
    const int sq = s & (QT - 1);

    uint4 p0a, p1a, p0b, p1b;                 // {half0,half1} x {plane0,plane1}
    float l0, l1;

#define ALOAD(KT)                                                                 \
    {                                                                             \
        const int pb0_ = ((bIdx * NH + (KT)) * NQT + qt8) * 2;                    \
        const bf16* q0_ = po + (size_t)pb0_ * QT * HD + sq * HD;                  \
        const bf16* q1_ = po + (size_t)(pb0_ + 1) * QT * HD + sq * HD;            \
        p0a = *(const uint4*)(q0_ + acol);                                        \
        p0b = *(const uint4*)(q0_ + 32 + acol);                                   \
        p1a = *(const uint4*)(q1_ + acol);                                        \
        p1b = *(const uint4*)(q1_ + 32 + acol);                                   \
        l0 = pl[(size_t)pb0_ * QT + sq];                                          \
        l1 = pl[(size_t)(pb0_ + 1) * QT + sq];                                    \
    }

    ALOAD(0);

    for (int kt = 0; kt < NH; kt++) {         // 16 iterations, k0 = kt*64, h = kt
        __syncthreads();                      // prev readers done
        // ---- commit A (fused combine) ----
        {
            const float inv = 1.0f / fmaxf(l0 + l1, 1e-30f);
            const bf16* x0 = (const bf16*)&p0a; const bf16* y0 = (const bf16*)&p1a;
            const bf16* x1 = (const bf16*)&p0b; const bf16* y1 = (const bf16*)&p1b;
            bf16 o0[8], o1[8];
#pragma unroll
            for (int e = 0; e < 8; e++) {
                o0[e] = __float2bfloat16((__bfloat162float(x0[e]) + __bfloat162float(y0[e])) * inv);
                o1[e] = __float2bfloat16((__bfloat162float(x1[e]) + __bfloat162float(y1[e])) * inv);
            }
            *(uint4*)(As + 0 * 2048 + arow * 32 + acol) = *(const uint4*)o0;
            *(uint4*)(As + 1 * 2048 + arow * 32 + acol) = *(const uint4*)o1;
        }
        // ---- B glds16 staging ----
#pragma unroll
        for (int n = 0; n < 4; n++) {
            const int c = wave * 4 + n;
            const int plane = c >> 3;
            const int cc = c & 7;
            glds16(Wob + (size_t)(bn + cc * 16 + srow) * SIZE + kt * 64 + plane * 32 + scol,
                   Bs + c * 512);
        }
        __syncthreads();                      // drain ds_write + glds16

        if (kt + 1 < NH) ALOAD(kt + 1);       // prefetch flows under MFMAs

#pragma unroll
        for (int kk = 0; kk < 2; kk++) {
            frag16 a[4], b[2];
#pragma unroll
            for (int mi = 0; mi < 4; mi++)
                a[mi] = *(const frag16*)(As + kk * 2048 + (mi * 16 + lane15) * 32 + quad * 8);
#pragma unroll
            for (int ni = 0; ni < 2; ni++)
                b[ni] = *(const frag16*)(Bs + kk * 4096 + (wn + ni * 16 + lane15) * 32 + quad * 8);
#pragma unroll
            for (int mi = 0; mi < 4; mi++)
#pragma unroll
                for (int ni = 0; ni < 2; ni++)
                    acc[mi][ni] = __builtin_amdgcn_mfma_f32_16x16x32_bf16(
                        a[mi], b[ni], acc[mi][ni], 0, 0, 0);
        }
    }
#undef ALOAD

#pragma unroll
    for (int ni = 0; ni < 2; ni++) {
        const int col = bn + wn + ni * 16 + lane15;
        const float bv = bo[col];
#pragma unroll
        for (int mi = 0; mi < 4; mi++) {
            const int row = bm + mi * 16 + quad * 4;
#pragma unroll
            for (int r = 0; r < 4; r++)
                out[(size_t)(row + r) * SIZE + col] = acc[mi][ni][r] + bv;
        }
    }
}

extern "C" void kernel_launch(void* const* d_in, const int* in_sizes, int n_in,
                              void* d_out, int out_size, void* d_ws, size_t ws_size,
                              hipStream_t stream) {
    const float* q  = (const float*)d_in[0];
    const float* k  = (const float*)d_in[1];
    const float* v  = (const float*)d_in[2];
    const float* Wq = (const float*)d_in[3];
    const float* bq = (const float*)d_in[4];
    const float* Wk = (const float*)d_in[5];
    const float* bk = (const float*)d_in[6];
    const float* Wv = (const float*)d_in[7];
    const float* bv = (const float*)d_in[8];
    const float* Wo = (const float*)d_in[9];
    const float* bo = (const float*)d_in[10];
    float* out = (float*)d_out;

    // ws (bf16): Wb[4M] | qb | kb | vb | qh | kh | vt  (4.19M elems each)
    // aliases: po (8.39M) = qb+kb (dead after qkv); pl = Wq slot (dead after qkv)
    bf16* Wb  = (bf16*)d_ws;
    bf16* qb  = Wb + (size_t)4 * SIZE * SIZE;
    bf16* kb  = qb + (size_t)MROWS * SIZE;
    bf16* vb  = kb + (size_t)MROWS * SIZE;
    bf16* qh  = vb + (size_t)MROWS * SIZE;
    bf16* kh  = qh + (size_t)MROWS * SIZE;
    bf16* vt  = kh + (size_t)MROWS * SIZE;
    bf16* po  = qb;
    float* pl = (float*)Wb;

    cast_kernel<<<dim3(8192, 1, 1), 256, 0, stream>>>(
        Wq, Wk, Wv, Wo, q, k, v, Wb, qb, kb, vb);
    qkv_proj_kernel<<<dim3(768, 1, 1), 256, 0, stream>>>(
        qb, kb, vb, Wb, bq, bk, bv, qh, kh, vt);
    attn_kernel<<<dim3(1024, 1, 1), 256, 0, stream>>>(qh, kh, vt, po, pl);
    out_proj_kernel<<<dim3(512, 1, 1), 256, 0, stream>>>(
        po, pl, Wb + (size_t)3 * SIZE * SIZE, bo, out);
}